// Round 2
// baseline (1300.731 us; speedup 1.0000x reference)
//
#include <hip/hip_runtime.h>
#include <hip/hip_bf16.h>

typedef __hip_bfloat16 bf16;

#define DIMC 128
#define NH 8
#define HD 16
#define HSZ 128
#define WSZ 128
#define HW (HSZ*WSZ)
#define CI_EXT 147   // 128 x | 8 cond | lpan | pan | pan-lpan | 8 ms
#define COUT 640     // 128 q | 128 k_pan | 128 v_pan | 128 k_ms | 128 v_ms

static __device__ __forceinline__ float b2f(bf16 v) { return __bfloat162float(v); }
static __device__ __forceinline__ bf16 f2b(float v) { return __float2bfloat16(v); }

// ---------------------------------------------------------------- prep X_ext
__global__ __launch_bounds__(256) void k_prep(
    const float* __restrict__ x, const float* __restrict__ ms,
    const float* __restrict__ lpan, const float* __restrict__ pan,
    const float* __restrict__ s, bf16* __restrict__ xext, int B) {
  int idx = blockIdx.x * 256 + threadIdx.x;
  int total = B * CI_EXT * HW;
  if (idx >= total) return;
  int p = idx % HW;
  int c = (idx / HW) % CI_EXT;
  int b = idx / (HW * CI_EXT);
  float v;
  if (c < 128) {
    v = x[((size_t)b * 128 + c) * HW + p];
  } else if (c < 136) {
    float sv = s[b];
    v = lpan[(size_t)b * HW + p] * (1.f - sv) +
        ms[((size_t)b * 8 + (c - 128)) * HW + p] * sv;
  } else if (c == 136) {
    v = lpan[(size_t)b * HW + p];
  } else if (c == 137) {
    v = pan[(size_t)b * HW + p];
  } else if (c == 138) {
    v = pan[(size_t)b * HW + p] - lpan[(size_t)b * HW + p];
  } else {
    v = ms[((size_t)b * 8 + (c - 139)) * HW + p];
  }
  xext[idx] = f2b(v);
}

// ---------------------------------------------------------------- pack weights
// Wpack layout: [(ci*9+tap)*640 + co], zero-filled where conv doesn't use ci.
__global__ __launch_bounds__(256) void k_pack(
    const float* __restrict__ qw, const float* __restrict__ qb,
    const float* __restrict__ kpw, const float* __restrict__ kpb,
    const float* __restrict__ vpw, const float* __restrict__ vpb,
    const float* __restrict__ kvw, const float* __restrict__ kvb,
    bf16* __restrict__ wpack, float* __restrict__ bpack) {
  int idx = blockIdx.x * 256 + threadIdx.x;
  const int total = CI_EXT * 9 * COUT;
  if (idx < total) {
    int co = idx % COUT;
    int ct = idx / COUT;
    int tap = ct % 9;
    int ci = ct / 9;
    float v = 0.f;
    if (co < 128) {                 // q: in = [x(0..127), cond(128..135)]
      if (ci < 136) v = qw[((size_t)co * 136 + ci) * 9 + tap];
    } else if (co < 256) {          // k_pan: in = [x, lpan]; lpan at ext 136
      int o = co - 128;
      if (ci < 128) v = kpw[((size_t)o * 129 + ci) * 9 + tap];
      else if (ci == 136) v = kpw[((size_t)o * 129 + 128) * 9 + tap];
    } else if (co < 384) {          // v_pan: [x, lpan, pan, pan-lpan] at 136..138
      int o = co - 256;
      if (ci < 128) v = vpw[((size_t)o * 131 + ci) * 9 + tap];
      else if (ci >= 136 && ci <= 138)
        v = vpw[((size_t)o * 131 + 128 + (ci - 136)) * 9 + tap];
    } else {                        // kv_ms: [x, ms]; ms at ext 139..146
      int o = co - 384;
      if (ci < 128) v = kvw[((size_t)o * 136 + ci) * 9 + tap];
      else if (ci >= 139) v = kvw[((size_t)o * 136 + 128 + (ci - 139)) * 9 + tap];
    }
    wpack[idx] = f2b(v);
  }
  if (idx < COUT) {
    float bv;
    if (idx < 128) bv = qb[idx];
    else if (idx < 256) bv = kpb[idx - 128];
    else if (idx < 384) bv = vpb[idx - 256];
    else bv = kvb[idx - 384];
    bpack[idx] = bv;
  }
}

// ---------------------------------------------------------------- big conv
// Block: 64 out-channels x (8x8) pixels. Thread: 4 co x 4 px.
__global__ __launch_bounds__(256) void k_conv(
    const bf16* __restrict__ xext, const bf16* __restrict__ wpack,
    const float* __restrict__ bpack, bf16* __restrict__ Y, int B) {
  __shared__ __align__(16) float in_t[8][100];      // [ci][row*10+col]
  __shared__ __align__(16) float w_t[8 * 9 * 64];   // [ci][tap][co]
  int tid = threadIdx.x;
  int bx = blockIdx.x;
  int tx0 = (bx & 15) * 8, ty0 = (bx >> 4) * 8;
  int co0 = blockIdx.y * 64;
  int b = blockIdx.z;
  int pg = tid & 15, cg = tid >> 4;
  int px0 = (pg & 1) * 4, py = pg >> 1;
  float acc[4][4];
#pragma unroll
  for (int i = 0; i < 4; i++)
#pragma unroll
    for (int j = 0; j < 4; j++) acc[i][j] = 0.f;

  const bf16* xb = xext + (size_t)b * CI_EXT * HW;

  for (int ci0 = 0; ci0 < CI_EXT; ci0 += 8) {
    int cnt = min(8, CI_EXT - ci0);
    for (int i = tid; i < cnt * 100; i += 256) {
      int ci = i / 100;
      int rc = i - ci * 100;
      int r = rc / 10, c = rc - r * 10;
      int gy = ty0 + r - 1, gx = tx0 + c - 1;
      float v = 0.f;
      if (gy >= 0 && gy < HSZ && gx >= 0 && gx < WSZ)
        v = b2f(xb[(size_t)(ci0 + ci) * HW + gy * WSZ + gx]);
      in_t[ci][rc] = v;
    }
    for (int i = tid; i < cnt * 9 * 64; i += 256) {
      int co_i = i & 63;
      int ct = i >> 6;  // ci*9+tap (relative)
      w_t[ct * 64 + co_i] = b2f(wpack[(size_t)(ci0 * 9 + ct) * COUT + co0 + co_i]);
    }
    __syncthreads();
    for (int ci = 0; ci < cnt; ci++) {
#pragma unroll
      for (int ky = 0; ky < 3; ky++) {
        float iv[6];
#pragma unroll
        for (int j = 0; j < 6; j++) iv[j] = in_t[ci][(py + ky) * 10 + px0 + j];
#pragma unroll
        for (int kx = 0; kx < 3; kx++) {
          const float4 wv = *(const float4*)&w_t[(ci * 9 + ky * 3 + kx) * 64 + cg * 4];
#pragma unroll
          for (int j = 0; j < 4; j++) {
            acc[0][j] += wv.x * iv[kx + j];
            acc[1][j] += wv.y * iv[kx + j];
            acc[2][j] += wv.z * iv[kx + j];
            acc[3][j] += wv.w * iv[kx + j];
          }
        }
      }
    }
    __syncthreads();
  }
#pragma unroll
  for (int ic = 0; ic < 4; ic++) {
    int co = co0 + cg * 4 + ic;
    float bv = bpack[co];
    bf16* dst = Y + ((size_t)b * COUT + co) * HW + (ty0 + py) * WSZ + tx0 + px0;
#pragma unroll
    for (int j = 0; j < 4; j++) dst[j] = f2b(acc[ic][j] + bv);
  }
}

// ---------------------------------------------------------------- depthwise + attention
// One thread per (b, src, head, pixel). Y channels: q 0-127 | k_pan 128 | v_pan 256 |
// k_ms 384 | v_ms 512.
__global__ __launch_bounds__(256) void k_attn(
    const bf16* __restrict__ Y, const float* __restrict__ dep_w,
    const float* __restrict__ dep_b, float* __restrict__ att, int B) {
  __shared__ float dw[144 * 9];
  __shared__ float db[144];
  for (int i = threadIdx.x; i < 144 * 9; i += 256) dw[i] = dep_w[i];
  for (int i = threadIdx.x; i < 144; i += 256) db[i] = dep_b[i];
  __syncthreads();
  int p = blockIdx.x * 256 + threadIdx.x;
  int n = blockIdx.y & 7, sp = blockIdx.y >> 3;
  int b = blockIdx.z;
  int h = p >> 7, w = p & 127;
  int qch = n * HD;
  int kch = (sp ? 384 : 128) + n * HD;
  int vch = (sp ? 512 : 256) + n * HD;
  const bf16* Yb = Y + (size_t)b * COUT * HW;

  float q[HD];
#pragma unroll
  for (int d = 0; d < HD; d++) q[d] = 0.25f * b2f(Yb[(size_t)(qch + d) * HW + p]);

  float logits[9];
#pragma unroll
  for (int a = 0; a < 9; a++) logits[a] = 0.f;

  for (int d = 0; d < HD; d++) {
    float patch[9];
    const bf16* src = Yb + (size_t)(kch + d) * HW;
#pragma unroll
    for (int ky = 0; ky < 3; ky++)
#pragma unroll
      for (int kx = 0; kx < 3; kx++) {
        int yy = h + ky - 1, xx = w + kx - 1;
        patch[ky * 3 + kx] =
            (yy >= 0 && yy < HSZ && xx >= 0 && xx < WSZ) ? b2f(src[yy * WSZ + xx]) : 0.f;
      }
#pragma unroll
    for (int a = 0; a < 9; a++) {
      float t = db[d * 9 + a];
#pragma unroll
      for (int tap = 0; tap < 9; tap++) t += dw[(d * 9 + a) * 9 + tap] * patch[tap];
      logits[a] += q[d] * t;
    }
  }
  float m = logits[0];
#pragma unroll
  for (int a = 1; a < 9; a++) m = fmaxf(m, logits[a]);
  float attnw[9];
  float ssum = 0.f;
#pragma unroll
  for (int a = 0; a < 9; a++) { attnw[a] = __expf(logits[a] - m); ssum += attnw[a]; }
  float inv = 1.f / ssum;
#pragma unroll
  for (int a = 0; a < 9; a++) attnw[a] *= inv;

  float* dst = att + (((size_t)b * 2 + sp) * DIMC + n * HD) * HW + p;
  for (int d = 0; d < HD; d++) {
    float patch[9];
    const bf16* src = Yb + (size_t)(vch + d) * HW;
#pragma unroll
    for (int ky = 0; ky < 3; ky++)
#pragma unroll
      for (int kx = 0; kx < 3; kx++) {
        int yy = h + ky - 1, xx = w + kx - 1;
        patch[ky * 3 + kx] =
            (yy >= 0 && yy < HSZ && xx >= 0 && xx < WSZ) ? b2f(src[yy * WSZ + xx]) : 0.f;
      }
    float o = 0.f;
#pragma unroll
    for (int a = 0; a < 9; a++) {
      float t = db[d * 9 + a];
#pragma unroll
      for (int tap = 0; tap < 9; tap++) t += dw[(d * 9 + a) * 9 + tap] * patch[tap];
      o += attnw[a] * t;
    }
    dst[(size_t)d * HW] = o;
  }
}

// ---------------------------------------------------------------- 1x1 proj
__global__ __launch_bounds__(256) void k_proj(
    const float* __restrict__ att, const float* __restrict__ w_pan,
    const float* __restrict__ b_pan, const float* __restrict__ w_ms,
    const float* __restrict__ b_ms, float* __restrict__ out, int B) {
  __shared__ float a_t[128][16];
  int p0 = blockIdx.x * 16;
  int bs = blockIdx.y;
  int b = bs >> 1, sp = bs & 1;
  const float* w = sp ? w_ms : w_pan;
  const float* bias = sp ? b_ms : b_pan;
  const float* src = att + ((size_t)b * 2 + sp) * DIMC * HW;
  for (int i = threadIdx.x; i < 128 * 16; i += 256) {
    int ci = i >> 4, px = i & 15;
    a_t[ci][px] = src[(size_t)ci * HW + p0 + px];
  }
  __syncthreads();
  int co = threadIdx.x & 127;
  int pg = threadIdx.x >> 7;
  float bv = bias[co];
  float acc[8];
#pragma unroll
  for (int j = 0; j < 8; j++) acc[j] = bv;
  for (int ci = 0; ci < 128; ci++) {
    float wv = w[co * 128 + ci];
#pragma unroll
    for (int j = 0; j < 8; j++) acc[j] += wv * a_t[ci][pg * 8 + j];
  }
  float* dst = out + (size_t)sp * B * DIMC * HW + (size_t)b * DIMC * HW +
               (size_t)co * HW + p0 + pg * 8;
#pragma unroll
  for (int j = 0; j < 8; j++) dst[j] = acc[j];
}

// ---------------------------------------------------------------- launch
extern "C" void kernel_launch(void* const* d_in, const int* in_sizes, int n_in,
                              void* d_out, int out_size, void* d_ws, size_t ws_size,
                              hipStream_t stream) {
  const float* x = (const float*)d_in[0];
  const float* ms = (const float*)d_in[1];
  const float* lpan = (const float*)d_in[2];
  const float* pan = (const float*)d_in[3];
  const float* s = (const float*)d_in[4];
  const float* q_w = (const float*)d_in[5];
  const float* q_b = (const float*)d_in[6];
  const float* k_pan_w = (const float*)d_in[7];
  const float* k_pan_b = (const float*)d_in[8];
  const float* v_pan_w = (const float*)d_in[9];
  const float* v_pan_b = (const float*)d_in[10];
  const float* kv_ms_w = (const float*)d_in[11];
  const float* kv_ms_b = (const float*)d_in[12];
  const float* dep_w = (const float*)d_in[13];
  const float* dep_b = (const float*)d_in[14];
  const float* pp_w = (const float*)d_in[15];
  const float* pp_b = (const float*)d_in[16];
  const float* pm_w = (const float*)d_in[17];
  const float* pm_b = (const float*)d_in[18];
  int B = in_sizes[0] / (DIMC * HW);

  char* ws = (char*)d_ws;
  size_t off = 0;
  auto alloc = [&](size_t bytes) -> void* {
    void* pptr = ws + off;
    off = (off + bytes + 255) & ~(size_t)255;
    return pptr;
  };
  bf16* xext = (bf16*)alloc((size_t)B * CI_EXT * HW * sizeof(bf16));
  bf16* wpack = (bf16*)alloc((size_t)CI_EXT * 9 * COUT * sizeof(bf16));
  float* bpack = (float*)alloc((size_t)COUT * sizeof(float));
  bf16* Y = (bf16*)alloc((size_t)B * COUT * HW * sizeof(bf16));
  float* att = (float*)alloc((size_t)B * 2 * DIMC * HW * sizeof(float));
  (void)ws_size; (void)n_in; (void)out_size;

  k_prep<<<dim3((B * CI_EXT * HW + 255) / 256), 256, 0, stream>>>(
      x, ms, lpan, pan, s, xext, B);
  k_pack<<<dim3((CI_EXT * 9 * COUT + 255) / 256), 256, 0, stream>>>(
      q_w, q_b, k_pan_w, k_pan_b, v_pan_w, v_pan_b, kv_ms_w, kv_ms_b, wpack, bpack);
  k_conv<<<dim3(256, COUT / 64, B), 256, 0, stream>>>(xext, wpack, bpack, Y, B);
  k_attn<<<dim3(HW / 256, 2 * NH, B), 256, 0, stream>>>(Y, dep_w, dep_b, att, B);
  k_proj<<<dim3(HW / 16, 2 * B), 256, 0, stream>>>(att, pp_w, pp_b, pm_w, pm_b,
                                                   (float*)d_out, B);
}

// Round 3
// 482.263 us; speedup vs baseline: 2.6971x; 2.6971x over previous
//
#include <hip/hip_runtime.h>
#include <hip/hip_bf16.h>

typedef __hip_bfloat16 bf16;
typedef unsigned short ushort_t;
typedef __attribute__((ext_vector_type(8))) __bf16 bf16x8;
typedef __attribute__((ext_vector_type(4))) float f32x4;

#define DIMC 128
#define NH 8
#define HD 16
#define HSZ 128
#define WSZ 128
#define HW (HSZ*WSZ)
#define CI_PAD 160    // 147 real ext channels, padded to 160 (mult of 32)
#define KTOT (9*CI_PAD)   // 1440
#define COUT 640      // 128 q | 128 k_pan | 128 v_pan | 128 k_ms | 128 v_ms
#define PROW 130      // padded image dim (1 halo each side)
#define NPIX (PROW*PROW)

static __device__ __forceinline__ float b2f(bf16 v) { return __bfloat162float(v); }
static __device__ __forceinline__ bf16 f2b(float v) { return __float2bfloat16(v); }
static __device__ __forceinline__ ushort_t f2bu(float v) {
  bf16 t = __float2bfloat16(v);
  return *reinterpret_cast<ushort_t*>(&t);
}

// ---------------------------------------------------------------- prep X_T
// X_T[b][yy*130+xx][ci] bf16, zero at borders and ci>=147.
// ext channels: 0-127 x | 128-135 cond | 136 lpan | 137 pan | 138 pan-lpan | 139-146 ms
__global__ __launch_bounds__(256) void k_prep(
    const float* __restrict__ x, const float* __restrict__ ms,
    const float* __restrict__ lpan, const float* __restrict__ pan,
    const float* __restrict__ s, ushort_t* __restrict__ xt, int B) {
  int idx = blockIdx.x * 256 + threadIdx.x;
  int total = B * NPIX * 20;
  if (idx >= total) return;
  int cig = idx % 20;
  int pr = (idx / 20) % NPIX;
  int b = idx / (20 * NPIX);
  int yy = pr / PROW, xx = pr % PROW;
  bool border = (yy == 0) | (yy == PROW - 1) | (xx == 0) | (xx == PROW - 1);
  int p = (yy - 1) * WSZ + (xx - 1);
  float sv = s[b];
  ushort_t vals[8];
#pragma unroll
  for (int i = 0; i < 8; i++) {
    int ci = cig * 8 + i;
    float v = 0.f;
    if (!border && ci < 147) {
      if (ci < 128) v = x[((size_t)b * 128 + ci) * HW + p];
      else if (ci < 136) v = lpan[(size_t)b * HW + p] * (1.f - sv) +
                             ms[((size_t)b * 8 + (ci - 128)) * HW + p] * sv;
      else if (ci == 136) v = lpan[(size_t)b * HW + p];
      else if (ci == 137) v = pan[(size_t)b * HW + p];
      else if (ci == 138) v = pan[(size_t)b * HW + p] - lpan[(size_t)b * HW + p];
      else v = ms[((size_t)b * 8 + (ci - 139)) * HW + p];
    }
    vals[i] = f2bu(v);
  }
  *(uint4*)(xt + ((size_t)b * NPIX + pr) * CI_PAD + cig * 8) = *(uint4*)vals;
}

// ---------------------------------------------------------------- pack weights
// wp2[co][tap*160+ci], zero-filled where conv doesn't use ci (and ci>=147).
__global__ __launch_bounds__(256) void k_pack(
    const float* __restrict__ qw, const float* __restrict__ qb,
    const float* __restrict__ kpw, const float* __restrict__ kpb,
    const float* __restrict__ vpw, const float* __restrict__ vpb,
    const float* __restrict__ kvw, const float* __restrict__ kvb,
    ushort_t* __restrict__ wp2, float* __restrict__ bpack) {
  int idx = blockIdx.x * 256 + threadIdx.x;
  const int total = COUT * KTOT;
  if (idx < total) {
    int co = idx / KTOT;
    int r = idx % KTOT;
    int tap = r / CI_PAD;
    int ci = r % CI_PAD;
    float v = 0.f;
    if (ci < 147) {
      if (co < 128) {                 // q: in = [x(0..127), cond(128..135)]
        if (ci < 136) v = qw[((size_t)co * 136 + ci) * 9 + tap];
      } else if (co < 256) {          // k_pan: [x, lpan]; lpan at ext 136
        int o = co - 128;
        if (ci < 128) v = kpw[((size_t)o * 129 + ci) * 9 + tap];
        else if (ci == 136) v = kpw[((size_t)o * 129 + 128) * 9 + tap];
      } else if (co < 384) {          // v_pan: [x, lpan, pan, pan-lpan] 136..138
        int o = co - 256;
        if (ci < 128) v = vpw[((size_t)o * 131 + ci) * 9 + tap];
        else if (ci >= 136 && ci <= 138)
          v = vpw[((size_t)o * 131 + 128 + (ci - 136)) * 9 + tap];
      } else {                        // kv_ms: [x, ms]; ms at ext 139..146
        int o = co - 384;
        if (ci < 128) v = kvw[((size_t)o * 136 + ci) * 9 + tap];
        else if (ci >= 139) v = kvw[((size_t)o * 136 + 128 + (ci - 139)) * 9 + tap];
      }
    }
    wp2[idx] = f2bu(v);
  }
  if (idx < COUT) {
    float bv;
    if (idx < 128) bv = qb[idx];
    else if (idx < 256) bv = kpb[idx - 128];
    else if (idx < 384) bv = vpb[idx - 256];
    else bv = kvb[idx - 384];
    bpack[idx] = bv;
  }
}

// ---------------------------------------------------------------- MFMA implicit GEMM conv
// C[co][px] = sum_{tap,ci} W[co][tap*160+ci] * X_T[(y+ky)*130 + px + kx][ci]
// Block: 128 co x 128 px (one image row). 4 waves in 2x2, each 64x64 via 4x4
// 16x16x32 MFMA tiles. BK=32.
__global__ __launch_bounds__(256) void k_conv_mfma(
    const ushort_t* __restrict__ xt, const ushort_t* __restrict__ wp2,
    const float* __restrict__ bpack, bf16* __restrict__ Y, int B) {
  __shared__ ushort_t As[128 * 32];   // [co][k]  64B rows
  __shared__ ushort_t Bs[128 * 32];   // [px][k]
  int tid = threadIdx.x;
  int lane = tid & 63;
  int wid = tid >> 6;
  int y = blockIdx.x;              // image row
  int co0 = blockIdx.y * 128;
  int b = blockIdx.z;
  const ushort_t* xtb = xt + (size_t)b * NPIX * CI_PAD;

  int wm = (wid >> 1) * 64, wn = (wid & 1) * 64;
  int l15 = lane & 15, q = lane >> 4, kq = q * 8;
  int ra = tid >> 1;               // staging row 0..127
  int hk = (tid & 1) * 16;         // staging k-offset (elements)

  f32x4 acc[4][4];
#pragma unroll
  for (int i = 0; i < 4; i++)
#pragma unroll
    for (int j = 0; j < 4; j++) acc[i][j] = (f32x4){0.f, 0.f, 0.f, 0.f};

  const ushort_t* wrow = wp2 + (size_t)(co0 + ra) * KTOT + hk;

  for (int tap = 0; tap < 9; ++tap) {
    int ky = tap / 3, kx = tap % 3;
    const ushort_t* xrow =
        xtb + ((size_t)(y + ky) * PROW + kx + ra) * CI_PAD + hk;
    for (int ci0 = 0; ci0 < CI_PAD; ci0 += 32) {
      const ushort_t* ga = wrow + tap * CI_PAD + ci0;
      const ushort_t* gb = xrow + ci0;
      uint4 a0 = *(const uint4*)ga;
      uint4 a1 = *(const uint4*)(ga + 8);
      uint4 b0 = *(const uint4*)gb;
      uint4 b1 = *(const uint4*)(gb + 8);
      __syncthreads();
      *(uint4*)&As[ra * 32 + hk] = a0;
      *(uint4*)&As[ra * 32 + hk + 8] = a1;
      *(uint4*)&Bs[ra * 32 + hk] = b0;
      *(uint4*)&Bs[ra * 32 + hk + 8] = b1;
      __syncthreads();
      bf16x8 af[4], bv[4];
#pragma unroll
      for (int t = 0; t < 4; t++)
        af[t] = *(const bf16x8*)&As[(wm + t * 16 + l15) * 32 + kq];
#pragma unroll
      for (int t = 0; t < 4; t++)
        bv[t] = *(const bf16x8*)&Bs[(wn + t * 16 + l15) * 32 + kq];
#pragma unroll
      for (int i = 0; i < 4; i++)
#pragma unroll
        for (int j = 0; j < 4; j++)
          acc[i][j] = __builtin_amdgcn_mfma_f32_16x16x32_bf16(af[i], bv[j],
                                                              acc[i][j], 0, 0, 0);
    }
  }

  // epilogue: D col = lane&15 (px), row = quad*4+reg (co)
#pragma unroll
  for (int i = 0; i < 4; i++) {
    int corow = co0 + wm + i * 16 + q * 4;
#pragma unroll
    for (int j = 0; j < 4; j++) {
      int px = wn + j * 16 + l15;
      size_t base = ((size_t)b * COUT + corow) * HW + y * WSZ + px;
#pragma unroll
      for (int r = 0; r < 4; r++)
        Y[base + (size_t)r * HW] = f2b(acc[i][j][r] + bpack[corow + r]);
    }
  }
}

// ---------------------------------------------------------------- depthwise + attention
__global__ __launch_bounds__(256) void k_attn(
    const bf16* __restrict__ Y, const float* __restrict__ dep_w,
    const float* __restrict__ dep_b, float* __restrict__ att, int B) {
  __shared__ float dw[144 * 9];
  __shared__ float db[144];
  for (int i = threadIdx.x; i < 144 * 9; i += 256) dw[i] = dep_w[i];
  for (int i = threadIdx.x; i < 144; i += 256) db[i] = dep_b[i];
  __syncthreads();
  int p = blockIdx.x * 256 + threadIdx.x;
  int n = blockIdx.y & 7, sp = blockIdx.y >> 3;
  int b = blockIdx.z;
  int h = p >> 7, w = p & 127;
  int qch = n * HD;
  int kch = (sp ? 384 : 128) + n * HD;
  int vch = (sp ? 512 : 256) + n * HD;
  const bf16* Yb = Y + (size_t)b * COUT * HW;

  float qv[HD];
#pragma unroll
  for (int d = 0; d < HD; d++) qv[d] = 0.25f * b2f(Yb[(size_t)(qch + d) * HW + p]);

  float logits[9];
#pragma unroll
  for (int a = 0; a < 9; a++) logits[a] = 0.f;

  for (int d = 0; d < HD; d++) {
    float patch[9];
    const bf16* src = Yb + (size_t)(kch + d) * HW;
#pragma unroll
    for (int ky = 0; ky < 3; ky++)
#pragma unroll
      for (int kx = 0; kx < 3; kx++) {
        int yy = h + ky - 1, xx = w + kx - 1;
        patch[ky * 3 + kx] =
            (yy >= 0 && yy < HSZ && xx >= 0 && xx < WSZ) ? b2f(src[yy * WSZ + xx]) : 0.f;
      }
#pragma unroll
    for (int a = 0; a < 9; a++) {
      float t = db[d * 9 + a];
#pragma unroll
      for (int tap = 0; tap < 9; tap++) t += dw[(d * 9 + a) * 9 + tap] * patch[tap];
      logits[a] += qv[d] * t;
    }
  }
  float m = logits[0];
#pragma unroll
  for (int a = 1; a < 9; a++) m = fmaxf(m, logits[a]);
  float attnw[9];
  float ssum = 0.f;
#pragma unroll
  for (int a = 0; a < 9; a++) { attnw[a] = __expf(logits[a] - m); ssum += attnw[a]; }
  float inv = 1.f / ssum;
#pragma unroll
  for (int a = 0; a < 9; a++) attnw[a] *= inv;

  float* dst = att + (((size_t)b * 2 + sp) * DIMC + n * HD) * HW + p;
  for (int d = 0; d < HD; d++) {
    float patch[9];
    const bf16* src = Yb + (size_t)(vch + d) * HW;
#pragma unroll
    for (int ky = 0; ky < 3; ky++)
#pragma unroll
      for (int kx = 0; kx < 3; kx++) {
        int yy = h + ky - 1, xx = w + kx - 1;
        patch[ky * 3 + kx] =
            (yy >= 0 && yy < HSZ && xx >= 0 && xx < WSZ) ? b2f(src[yy * WSZ + xx]) : 0.f;
      }
    float o = 0.f;
#pragma unroll
    for (int a = 0; a < 9; a++) {
      float t = db[d * 9 + a];
#pragma unroll
      for (int tap = 0; tap < 9; tap++) t += dw[(d * 9 + a) * 9 + tap] * patch[tap];
      o += attnw[a] * t;
    }
    dst[(size_t)d * HW] = o;
  }
}

// ---------------------------------------------------------------- 1x1 proj
__global__ __launch_bounds__(256) void k_proj(
    const float* __restrict__ att, const float* __restrict__ w_pan,
    const float* __restrict__ b_pan, const float* __restrict__ w_ms,
    const float* __restrict__ b_ms, float* __restrict__ out, int B) {
  __shared__ float a_t[128][16];
  int p0 = blockIdx.x * 16;
  int bs = blockIdx.y;
  int b = bs >> 1, sp = bs & 1;
  const float* w = sp ? w_ms : w_pan;
  const float* bias = sp ? b_ms : b_pan;
  const float* src = att + ((size_t)b * 2 + sp) * DIMC * HW;
  for (int i = threadIdx.x; i < 128 * 16; i += 256) {
    int ci = i >> 4, px = i & 15;
    a_t[ci][px] = src[(size_t)ci * HW + p0 + px];
  }
  __syncthreads();
  int co = threadIdx.x & 127;
  int pg = threadIdx.x >> 7;
  float bv = bias[co];
  float acc[8];
#pragma unroll
  for (int j = 0; j < 8; j++) acc[j] = bv;
  for (int ci = 0; ci < 128; ci++) {
    float wv = w[co * 128 + ci];
#pragma unroll
    for (int j = 0; j < 8; j++) acc[j] += wv * a_t[ci][pg * 8 + j];
  }
  float* dst = out + (size_t)sp * B * DIMC * HW + (size_t)b * DIMC * HW +
               (size_t)co * HW + p0 + pg * 8;
#pragma unroll
  for (int j = 0; j < 8; j++) dst[j] = acc[j];
}

// ---------------------------------------------------------------- launch
extern "C" void kernel_launch(void* const* d_in, const int* in_sizes, int n_in,
                              void* d_out, int out_size, void* d_ws, size_t ws_size,
                              hipStream_t stream) {
  const float* x = (const float*)d_in[0];
  const float* ms = (const float*)d_in[1];
  const float* lpan = (const float*)d_in[2];
  const float* pan = (const float*)d_in[3];
  const float* s = (const float*)d_in[4];
  const float* q_w = (const float*)d_in[5];
  const float* q_b = (const float*)d_in[6];
  const float* k_pan_w = (const float*)d_in[7];
  const float* k_pan_b = (const float*)d_in[8];
  const float* v_pan_w = (const float*)d_in[9];
  const float* v_pan_b = (const float*)d_in[10];
  const float* kv_ms_w = (const float*)d_in[11];
  const float* kv_ms_b = (const float*)d_in[12];
  const float* dep_w = (const float*)d_in[13];
  const float* dep_b = (const float*)d_in[14];
  const float* pp_w = (const float*)d_in[15];
  const float* pp_b = (const float*)d_in[16];
  const float* pm_w = (const float*)d_in[17];
  const float* pm_b = (const float*)d_in[18];
  int B = in_sizes[0] / (DIMC * HW);

  char* ws = (char*)d_ws;
  size_t off = 0;
  auto alloc = [&](size_t bytes) -> void* {
    void* pptr = ws + off;
    off = (off + bytes + 255) & ~(size_t)255;
    return pptr;
  };
  ushort_t* wp2 = (ushort_t*)alloc((size_t)COUT * KTOT * sizeof(ushort_t));
  float* bpack = (float*)alloc((size_t)COUT * sizeof(float));
  bf16* Y = (bf16*)alloc((size_t)B * COUT * HW * sizeof(bf16));
  // X_T and att share the tail region: X_T dead after k_conv, att written after.
  ushort_t* xt = (ushort_t*)(ws + off);
  float* att = (float*)(ws + off);
  (void)ws_size; (void)n_in; (void)out_size;

  k_prep<<<dim3((B * NPIX * 20 + 255) / 256), 256, 0, stream>>>(
      x, ms, lpan, pan, s, xt, B);
  k_pack<<<dim3((COUT * KTOT + 255) / 256), 256, 0, stream>>>(
      q_w, q_b, k_pan_w, k_pan_b, v_pan_w, v_pan_b, kv_ms_w, kv_ms_b, wp2, bpack);
  k_conv_mfma<<<dim3(HSZ, COUT / 128, B), 256, 0, stream>>>(xt, wp2, bpack, Y, B);
  k_attn<<<dim3(HW / 256, 2 * NH, B), 256, 0, stream>>>(Y, dep_w, dep_b, att, B);
  k_proj<<<dim3(HW / 16, 2 * B), 256, 0, stream>>>(att, pp_w, pp_b, pm_w, pm_b,
                                                   (float*)d_out, B);
}

// Round 4
// 405.089 us; speedup vs baseline: 3.2110x; 1.1905x over previous
//
#include <hip/hip_runtime.h>
#include <hip/hip_bf16.h>

typedef __hip_bfloat16 bf16;
typedef unsigned short ushort_t;
typedef __attribute__((ext_vector_type(8))) __bf16 bf16x8;
typedef __attribute__((ext_vector_type(4))) float f32x4;

#define DIMC 128
#define NH 8
#define HD 16
#define HSZ 128
#define WSZ 128
#define HW (HSZ*WSZ)
#define CI_PAD 160    // 147 real ext channels, padded to 160 (mult of 32)
#define KTOT (9*CI_PAD)   // 1440
#define COUT 640      // 128 q | 128 k_pan | 128 v_pan | 128 k_ms | 128 v_ms
#define PROW 130      // padded image dim (1 halo each side)
#define NPIX (PROW*PROW)

static __device__ __forceinline__ float b2f(bf16 v) { return __bfloat162float(v); }
static __device__ __forceinline__ bf16 f2b(float v) { return __float2bfloat16(v); }
static __device__ __forceinline__ ushort_t f2bu(float v) {
  bf16 t = __float2bfloat16(v);
  return *reinterpret_cast<ushort_t*>(&t);
}
static __device__ __forceinline__ float u2f(ushort_t u) {
  unsigned int w = ((unsigned int)u) << 16;
  float f;
  __builtin_memcpy(&f, &w, 4);
  return f;
}

// ---------------------------------------------------------------- prep X_T
// X_T[b][yy*130+xx][ci] bf16, zero at borders and ci>=147.
// ext channels: 0-127 x | 128-135 cond | 136 lpan | 137 pan | 138 pan-lpan | 139-146 ms
__global__ __launch_bounds__(256) void k_prep(
    const float* __restrict__ x, const float* __restrict__ ms,
    const float* __restrict__ lpan, const float* __restrict__ pan,
    const float* __restrict__ s, ushort_t* __restrict__ xt, int B) {
  int idx = blockIdx.x * 256 + threadIdx.x;
  int total = B * NPIX * 20;
  if (idx >= total) return;
  int cig = idx % 20;
  int pr = (idx / 20) % NPIX;
  int b = idx / (20 * NPIX);
  int yy = pr / PROW, xx = pr % PROW;
  bool border = (yy == 0) | (yy == PROW - 1) | (xx == 0) | (xx == PROW - 1);
  int p = (yy - 1) * WSZ + (xx - 1);
  float sv = s[b];
  ushort_t vals[8];
#pragma unroll
  for (int i = 0; i < 8; i++) {
    int ci = cig * 8 + i;
    float v = 0.f;
    if (!border && ci < 147) {
      if (ci < 128) v = x[((size_t)b * 128 + ci) * HW + p];
      else if (ci < 136) v = lpan[(size_t)b * HW + p] * (1.f - sv) +
                             ms[((size_t)b * 8 + (ci - 128)) * HW + p] * sv;
      else if (ci == 136) v = lpan[(size_t)b * HW + p];
      else if (ci == 137) v = pan[(size_t)b * HW + p];
      else if (ci == 138) v = pan[(size_t)b * HW + p] - lpan[(size_t)b * HW + p];
      else v = ms[((size_t)b * 8 + (ci - 139)) * HW + p];
    }
    vals[i] = f2bu(v);
  }
  *(uint4*)(xt + ((size_t)b * NPIX + pr) * CI_PAD + cig * 8) = *(uint4*)vals;
}

// ---------------------------------------------------------------- pack weights
// wp2[co][tap*160+ci], zero-filled where conv doesn't use ci (and ci>=147).
__global__ __launch_bounds__(256) void k_pack(
    const float* __restrict__ qw, const float* __restrict__ qb,
    const float* __restrict__ kpw, const float* __restrict__ kpb,
    const float* __restrict__ vpw, const float* __restrict__ vpb,
    const float* __restrict__ kvw, const float* __restrict__ kvb,
    ushort_t* __restrict__ wp2, float* __restrict__ bpack) {
  int idx = blockIdx.x * 256 + threadIdx.x;
  const int total = COUT * KTOT;
  if (idx < total) {
    int co = idx / KTOT;
    int r = idx % KTOT;
    int tap = r / CI_PAD;
    int ci = r % CI_PAD;
    float v = 0.f;
    if (ci < 147) {
      if (co < 128) {                 // q: in = [x(0..127), cond(128..135)]
        if (ci < 136) v = qw[((size_t)co * 136 + ci) * 9 + tap];
      } else if (co < 256) {          // k_pan: [x, lpan]; lpan at ext 136
        int o = co - 128;
        if (ci < 128) v = kpw[((size_t)o * 129 + ci) * 9 + tap];
        else if (ci == 136) v = kpw[((size_t)o * 129 + 128) * 9 + tap];
      } else if (co < 384) {          // v_pan: [x, lpan, pan, pan-lpan] 136..138
        int o = co - 256;
        if (ci < 128) v = vpw[((size_t)o * 131 + ci) * 9 + tap];
        else if (ci >= 136 && ci <= 138)
          v = vpw[((size_t)o * 131 + 128 + (ci - 136)) * 9 + tap];
      } else {                        // kv_ms: [x, ms]; ms at ext 139..146
        int o = co - 384;
        if (ci < 128) v = kvw[((size_t)o * 136 + ci) * 9 + tap];
        else if (ci >= 139) v = kvw[((size_t)o * 136 + 128 + (ci - 139)) * 9 + tap];
      }
    }
    wp2[idx] = f2bu(v);
  }
  if (idx < COUT) {
    float bv;
    if (idx < 128) bv = qb[idx];
    else if (idx < 256) bv = kpb[idx - 128];
    else if (idx < 384) bv = vpb[idx - 256];
    else bv = kvb[idx - 384];
    bpack[idx] = bv;
  }
}

// ---------------------------------------------------------------- MFMA implicit GEMM conv
__global__ __launch_bounds__(256) void k_conv_mfma(
    const ushort_t* __restrict__ xt, const ushort_t* __restrict__ wp2,
    const float* __restrict__ bpack, bf16* __restrict__ Y, int B) {
  __shared__ ushort_t As[128 * 32];   // [co][k]
  __shared__ ushort_t Bs[128 * 32];   // [px][k]
  int tid = threadIdx.x;
  int lane = tid & 63;
  int wid = tid >> 6;
  int y = blockIdx.x;              // image row
  int co0 = blockIdx.y * 128;
  int b = blockIdx.z;
  const ushort_t* xtb = xt + (size_t)b * NPIX * CI_PAD;

  int wm = (wid >> 1) * 64, wn = (wid & 1) * 64;
  int l15 = lane & 15, q = lane >> 4, kq = q * 8;
  int ra = tid >> 1;               // staging row 0..127
  int hk = (tid & 1) * 16;         // staging k-offset (elements)

  f32x4 acc[4][4];
#pragma unroll
  for (int i = 0; i < 4; i++)
#pragma unroll
    for (int j = 0; j < 4; j++) acc[i][j] = (f32x4){0.f, 0.f, 0.f, 0.f};

  const ushort_t* wrow = wp2 + (size_t)(co0 + ra) * KTOT + hk;

  for (int tap = 0; tap < 9; ++tap) {
    int ky = tap / 3, kx = tap % 3;
    const ushort_t* xrow =
        xtb + ((size_t)(y + ky) * PROW + kx + ra) * CI_PAD + hk;
    for (int ci0 = 0; ci0 < CI_PAD; ci0 += 32) {
      const ushort_t* ga = wrow + tap * CI_PAD + ci0;
      const ushort_t* gb = xrow + ci0;
      uint4 a0 = *(const uint4*)ga;
      uint4 a1 = *(const uint4*)(ga + 8);
      uint4 b0 = *(const uint4*)gb;
      uint4 b1 = *(const uint4*)(gb + 8);
      __syncthreads();
      *(uint4*)&As[ra * 32 + hk] = a0;
      *(uint4*)&As[ra * 32 + hk + 8] = a1;
      *(uint4*)&Bs[ra * 32 + hk] = b0;
      *(uint4*)&Bs[ra * 32 + hk + 8] = b1;
      __syncthreads();
      bf16x8 af[4], bv[4];
#pragma unroll
      for (int t = 0; t < 4; t++)
        af[t] = *(const bf16x8*)&As[(wm + t * 16 + l15) * 32 + kq];
#pragma unroll
      for (int t = 0; t < 4; t++)
        bv[t] = *(const bf16x8*)&Bs[(wn + t * 16 + l15) * 32 + kq];
#pragma unroll
      for (int i = 0; i < 4; i++)
#pragma unroll
        for (int j = 0; j < 4; j++)
          acc[i][j] = __builtin_amdgcn_mfma_f32_16x16x32_bf16(af[i], bv[j],
                                                              acc[i][j], 0, 0, 0);
    }
  }

#pragma unroll
  for (int i = 0; i < 4; i++) {
    int corow = co0 + wm + i * 16 + q * 4;
#pragma unroll
    for (int j = 0; j < 4; j++) {
      int px = wn + j * 16 + l15;
      size_t base = ((size_t)b * COUT + corow) * HW + y * WSZ + px;
#pragma unroll
      for (int r = 0; r < 4; r++)
        Y[base + (size_t)r * HW] = f2b(acc[i][j][r] + bpack[corow + r]);
    }
  }
}

// ---------------------------------------------------------------- depthwise + attention
// Block: one (b, src, head) x (4 rows x 128 cols). Thread: 2 adjacent px.
// LDS tile: 16 ch x 6 rows (halo) x 144 (col c at index 8+c; halo idx 7,136).
__global__ __launch_bounds__(256) void k_attn(
    const bf16* __restrict__ Y, const float* __restrict__ dep_w,
    const float* __restrict__ dep_b, float* __restrict__ att, int B) {
  __shared__ ushort_t tile[16 * 6 * 144];
  int tid = threadIdx.x;
  int sp = blockIdx.y >> 3, n = blockIdx.y & 7;
  int b = blockIdx.z;
  int y0 = blockIdx.x * 4;
  int qch = n * HD;
  int kch = (sp ? 384 : 128) + n * HD;
  int vch = (sp ? 512 : 256) + n * HD;
  const bf16* Yb = Y + (size_t)b * COUT * HW;

  int r = tid >> 6;          // row in tile 0..3
  int c0 = (tid & 63) * 2;   // col 0..126
  int p0 = (y0 + r) * WSZ + c0;

  // ---- stage K channels
  auto stage = [&](int ch0) {
    for (int i = tid; i < 16 * 6 * 16; i += 256) {
      int ch = i / 96;
      int rem = i - ch * 96;
      int rr = rem >> 4, c8 = rem & 15;
      int yy = y0 - 1 + rr;
      uint4 v = {0u, 0u, 0u, 0u};
      if (yy >= 0 && yy < HSZ)
        v = *(const uint4*)(Yb + (size_t)(ch0 + ch) * HW + yy * WSZ + c8 * 8);
      *(uint4*)&tile[(ch * 6 + rr) * 144 + 8 + c8 * 8] = v;
    }
    for (int i = tid; i < 16 * 6 * 2; i += 256) {
      int ch = i / 12;
      int rem = i - ch * 12;
      int rr = rem >> 1, side = rem & 1;
      tile[(ch * 6 + rr) * 144 + (side ? 136 : 7)] = 0;
    }
  };

  stage(kch);
  __syncthreads();

  float logits[2][9];
#pragma unroll
  for (int a = 0; a < 9; a++) { logits[0][a] = 0.f; logits[1][a] = 0.f; }

#pragma unroll 4
  for (int d = 0; d < 16; d++) {
    float pt[3][4];
#pragma unroll
    for (int ry = 0; ry < 3; ry++)
#pragma unroll
      for (int cc = 0; cc < 4; cc++)
        pt[ry][cc] = u2f(tile[(d * 6 + r + ry) * 144 + 7 + c0 + cc]);
    float q0 = 0.25f * b2f(Yb[(size_t)(qch + d) * HW + p0]);
    float q1 = 0.25f * b2f(Yb[(size_t)(qch + d) * HW + p0 + 1]);
#pragma unroll
    for (int a = 0; a < 9; a++) {
      const float* wr = dep_w + (d * 9 + a) * 9;   // uniform -> s_load
      float bb = dep_b[d * 9 + a];
      float t0 = bb, t1 = bb;
#pragma unroll
      for (int ky = 0; ky < 3; ky++)
#pragma unroll
        for (int kx = 0; kx < 3; kx++) {
          float wv = wr[ky * 3 + kx];
          t0 += wv * pt[ky][kx];
          t1 += wv * pt[ky][kx + 1];
        }
      logits[0][a] += q0 * t0;
      logits[1][a] += q1 * t1;
    }
  }

  float aw[2][9];
#pragma unroll
  for (int px = 0; px < 2; px++) {
    float m = logits[px][0];
#pragma unroll
    for (int a = 1; a < 9; a++) m = fmaxf(m, logits[px][a]);
    float ssum = 0.f;
#pragma unroll
    for (int a = 0; a < 9; a++) { aw[px][a] = __expf(logits[px][a] - m); ssum += aw[px][a]; }
    float inv = 1.f / ssum;
#pragma unroll
    for (int a = 0; a < 9; a++) aw[px][a] *= inv;
  }

  __syncthreads();
  stage(vch);
  __syncthreads();

  float* dst = att + (((size_t)b * 2 + sp) * DIMC + n * HD) * HW;
#pragma unroll 4
  for (int d = 0; d < 16; d++) {
    float pt[3][4];
#pragma unroll
    for (int ry = 0; ry < 3; ry++)
#pragma unroll
      for (int cc = 0; cc < 4; cc++)
        pt[ry][cc] = u2f(tile[(d * 6 + r + ry) * 144 + 7 + c0 + cc]);
    float o0 = 0.f, o1 = 0.f;
#pragma unroll
    for (int a = 0; a < 9; a++) {
      const float* wr = dep_w + (d * 9 + a) * 9;
      float bb = dep_b[d * 9 + a];
      float t0 = bb, t1 = bb;
#pragma unroll
      for (int ky = 0; ky < 3; ky++)
#pragma unroll
        for (int kx = 0; kx < 3; kx++) {
          float wv = wr[ky * 3 + kx];
          t0 += wv * pt[ky][kx];
          t1 += wv * pt[ky][kx + 1];
        }
      o0 += aw[0][a] * t0;
      o1 += aw[1][a] * t1;
    }
    float2 ov = {o0, o1};
    *(float2*)&dst[(size_t)d * HW + p0] = ov;
  }
}

// ---------------------------------------------------------------- 1x1 proj
__global__ __launch_bounds__(256) void k_proj(
    const float* __restrict__ att, const float* __restrict__ w_pan,
    const float* __restrict__ b_pan, const float* __restrict__ w_ms,
    const float* __restrict__ b_ms, float* __restrict__ out, int B) {
  __shared__ float a_t[128][16];
  int p0 = blockIdx.x * 16;
  int bs = blockIdx.y;
  int b = bs >> 1, sp = bs & 1;
  const float* w = sp ? w_ms : w_pan;
  const float* bias = sp ? b_ms : b_pan;
  const float* src = att + ((size_t)b * 2 + sp) * DIMC * HW;
  for (int i = threadIdx.x; i < 128 * 16; i += 256) {
    int ci = i >> 4, px = i & 15;
    a_t[ci][px] = src[(size_t)ci * HW + p0 + px];
  }
  __syncthreads();
  int co = threadIdx.x & 127;
  int pg = threadIdx.x >> 7;
  float bv = bias[co];
  float acc[8];
#pragma unroll
  for (int j = 0; j < 8; j++) acc[j] = bv;
  for (int ci = 0; ci < 128; ci++) {
    float wv = w[co * 128 + ci];
#pragma unroll
    for (int j = 0; j < 8; j++) acc[j] += wv * a_t[ci][pg * 8 + j];
  }
  float* dst = out + (size_t)sp * B * DIMC * HW + (size_t)b * DIMC * HW +
               (size_t)co * HW + p0 + pg * 8;
#pragma unroll
  for (int j = 0; j < 8; j++) dst[j] = acc[j];
}

// ---------------------------------------------------------------- launch
extern "C" void kernel_launch(void* const* d_in, const int* in_sizes, int n_in,
                              void* d_out, int out_size, void* d_ws, size_t ws_size,
                              hipStream_t stream) {
  const float* x = (const float*)d_in[0];
  const float* ms = (const float*)d_in[1];
  const float* lpan = (const float*)d_in[2];
  const float* pan = (const float*)d_in[3];
  const float* s = (const float*)d_in[4];
  const float* q_w = (const float*)d_in[5];
  const float* q_b = (const float*)d_in[6];
  const float* k_pan_w = (const float*)d_in[7];
  const float* k_pan_b = (const float*)d_in[8];
  const float* v_pan_w = (const float*)d_in[9];
  const float* v_pan_b = (const float*)d_in[10];
  const float* kv_ms_w = (const float*)d_in[11];
  const float* kv_ms_b = (const float*)d_in[12];
  const float* dep_w = (const float*)d_in[13];
  const float* dep_b = (const float*)d_in[14];
  const float* pp_w = (const float*)d_in[15];
  const float* pp_b = (const float*)d_in[16];
  const float* pm_w = (const float*)d_in[17];
  const float* pm_b = (const float*)d_in[18];
  int B = in_sizes[0] / (DIMC * HW);

  char* ws = (char*)d_ws;
  size_t off = 0;
  auto alloc = [&](size_t bytes) -> void* {
    void* pptr = ws + off;
    off = (off + bytes + 255) & ~(size_t)255;
    return pptr;
  };
  ushort_t* wp2 = (ushort_t*)alloc((size_t)COUT * KTOT * sizeof(ushort_t));
  float* bpack = (float*)alloc((size_t)COUT * sizeof(float));
  bf16* Y = (bf16*)alloc((size_t)B * COUT * HW * sizeof(bf16));
  // X_T and att share the tail region: X_T dead after k_conv, att written after.
  ushort_t* xt = (ushort_t*)(ws + off);
  float* att = (float*)(ws + off);
  (void)ws_size; (void)n_in; (void)out_size;

  k_prep<<<dim3((B * NPIX * 20 + 255) / 256), 256, 0, stream>>>(
      x, ms, lpan, pan, s, xt, B);
  k_pack<<<dim3((COUT * KTOT + 255) / 256), 256, 0, stream>>>(
      q_w, q_b, k_pan_w, k_pan_b, v_pan_w, v_pan_b, kv_ms_w, kv_ms_b, wp2, bpack);
  k_conv_mfma<<<dim3(HSZ, COUT / 128, B), 256, 0, stream>>>(xt, wp2, bpack, Y, B);
  k_attn<<<dim3(HSZ / 4, 2 * NH, B), 256, 0, stream>>>(Y, dep_w, dep_b, att, B);
  k_proj<<<dim3(HW / 16, 2 * B), 256, 0, stream>>>(att, pp_w, pp_b, pm_w, pm_b,
                                                   (float*)d_out, B);
}

// Round 5
// 370.343 us; speedup vs baseline: 3.5122x; 1.0938x over previous
//
#include <hip/hip_runtime.h>
#include <hip/hip_bf16.h>

typedef __hip_bfloat16 bf16;
typedef unsigned short ushort_t;
typedef __attribute__((ext_vector_type(8))) __bf16 bf16x8;
typedef __attribute__((ext_vector_type(4))) float f32x4;

#define DIMC 128
#define NH 8
#define HD 16
#define HSZ 128
#define WSZ 128
#define HW (HSZ*WSZ)
#define CI_PAD 160    // 147 real ext channels, padded to 160 (mult of 32)
#define KTOT (9*CI_PAD)   // 1440
#define COUT 640      // 128 q | 128 k_pan | 128 v_pan | 128 k_ms | 128 v_ms
#define PROW 130      // padded image dim (1 halo each side)
#define NPIX (PROW*PROW)

static __device__ __forceinline__ float b2f(bf16 v) { return __bfloat162float(v); }
static __device__ __forceinline__ bf16 f2b(float v) { return __float2bfloat16(v); }
static __device__ __forceinline__ ushort_t f2bu(float v) {
  bf16 t = __float2bfloat16(v);
  return *reinterpret_cast<ushort_t*>(&t);
}
static __device__ __forceinline__ float u2f(ushort_t u) {
  unsigned int w = ((unsigned int)u) << 16;
  float f;
  __builtin_memcpy(&f, &w, 4);
  return f;
}
// async global->LDS, 16B per lane; LDS dest = wave-uniform base + lane*16
static __device__ __forceinline__ void gl_lds16(const void* g, void* l) {
  __builtin_amdgcn_global_load_lds(
      (const __attribute__((address_space(1))) unsigned int*)g,
      (__attribute__((address_space(3))) unsigned int*)l, 16, 0, 0);
}

// ---------------------------------------------------------------- prep X_T
// X_T[b][yy*130+xx][ci] bf16, zero at borders and ci>=147.
// ext channels: 0-127 x | 128-135 cond | 136 lpan | 137 pan | 138 pan-lpan | 139-146 ms
__global__ __launch_bounds__(256) void k_prep(
    const float* __restrict__ x, const float* __restrict__ ms,
    const float* __restrict__ lpan, const float* __restrict__ pan,
    const float* __restrict__ s, ushort_t* __restrict__ xt, int B) {
  int idx = blockIdx.x * 256 + threadIdx.x;
  int total = B * NPIX * 20;
  if (idx >= total) return;
  int cig = idx % 20;
  int pr = (idx / 20) % NPIX;
  int b = idx / (20 * NPIX);
  int yy = pr / PROW, xx = pr % PROW;
  bool border = (yy == 0) | (yy == PROW - 1) | (xx == 0) | (xx == PROW - 1);
  int p = (yy - 1) * WSZ + (xx - 1);
  float sv = s[b];
  ushort_t vals[8];
#pragma unroll
  for (int i = 0; i < 8; i++) {
    int ci = cig * 8 + i;
    float v = 0.f;
    if (!border && ci < 147) {
      if (ci < 128) v = x[((size_t)b * 128 + ci) * HW + p];
      else if (ci < 136) v = lpan[(size_t)b * HW + p] * (1.f - sv) +
                             ms[((size_t)b * 8 + (ci - 128)) * HW + p] * sv;
      else if (ci == 136) v = lpan[(size_t)b * HW + p];
      else if (ci == 137) v = pan[(size_t)b * HW + p];
      else if (ci == 138) v = pan[(size_t)b * HW + p] - lpan[(size_t)b * HW + p];
      else v = ms[((size_t)b * 8 + (ci - 139)) * HW + p];
    }
    vals[i] = f2bu(v);
  }
  *(uint4*)(xt + ((size_t)b * NPIX + pr) * CI_PAD + cig * 8) = *(uint4*)vals;
}

// ---------------------------------------------------------------- pack weights
// wp2[co][tap*160+ci], zero-filled where conv doesn't use ci (and ci>=147).
__global__ __launch_bounds__(256) void k_pack(
    const float* __restrict__ qw, const float* __restrict__ qb,
    const float* __restrict__ kpw, const float* __restrict__ kpb,
    const float* __restrict__ vpw, const float* __restrict__ vpb,
    const float* __restrict__ kvw, const float* __restrict__ kvb,
    ushort_t* __restrict__ wp2, float* __restrict__ bpack) {
  int idx = blockIdx.x * 256 + threadIdx.x;
  const int total = COUT * KTOT;
  if (idx < total) {
    int co = idx / KTOT;
    int r = idx % KTOT;
    int tap = r / CI_PAD;
    int ci = r % CI_PAD;
    float v = 0.f;
    if (ci < 147) {
      if (co < 128) {                 // q: in = [x(0..127), cond(128..135)]
        if (ci < 136) v = qw[((size_t)co * 136 + ci) * 9 + tap];
      } else if (co < 256) {          // k_pan: [x, lpan]; lpan at ext 136
        int o = co - 128;
        if (ci < 128) v = kpw[((size_t)o * 129 + ci) * 9 + tap];
        else if (ci == 136) v = kpw[((size_t)o * 129 + 128) * 9 + tap];
      } else if (co < 384) {          // v_pan: [x, lpan, pan, pan-lpan] 136..138
        int o = co - 256;
        if (ci < 128) v = vpw[((size_t)o * 131 + ci) * 9 + tap];
        else if (ci >= 136 && ci <= 138)
          v = vpw[((size_t)o * 131 + 128 + (ci - 136)) * 9 + tap];
      } else {                        // kv_ms: [x, ms]; ms at ext 139..146
        int o = co - 384;
        if (ci < 128) v = kvw[((size_t)o * 136 + ci) * 9 + tap];
        else if (ci >= 139) v = kvw[((size_t)o * 136 + 128 + (ci - 139)) * 9 + tap];
      }
    }
    wp2[idx] = f2bu(v);
  }
  if (idx < COUT) {
    float bv;
    if (idx < 128) bv = qb[idx];
    else if (idx < 256) bv = kpb[idx - 128];
    else if (idx < 384) bv = vpb[idx - 256];
    else bv = kvb[idx - 384];
    bpack[idx] = bv;
  }
}

// ---------------------------------------------------------------- MFMA implicit GEMM conv
// C[co][px] = sum_{tap,ci} W[co][tap*160+ci] * X_T[(y+ky)*130 + px + kx][ci]
// Block: 128 co x 128 px (one image row); 4 waves 2x2; 64x64/wave; BK=32.
// Staging via global_load_lds width 16 (m97 structure).
__global__ __launch_bounds__(256) void k_conv_mfma(
    const ushort_t* __restrict__ xt, const ushort_t* __restrict__ wp2,
    const float* __restrict__ bpack, bf16* __restrict__ Y, int B) {
  __shared__ ushort_t As[128 * 32];   // [co][k]
  __shared__ ushort_t Bs[128 * 32];   // [px][k]
  int tid = threadIdx.x;
  int lane = tid & 63;
  int wid = tid >> 6;
  int y = blockIdx.x;              // image row
  int co0 = blockIdx.y * 128;
  int b = blockIdx.z;
  const ushort_t* xtb = xt + (size_t)b * NPIX * CI_PAD;

  int wm = (wid >> 1) * 64, wn = (wid & 1) * 64;
  int l15 = lane & 15, q = lane >> 4, kq = q * 8;
  int lrow = lane >> 2;            // 0..15: row within 16-row staging group
  int lq = lane & 3;               // 0..3: 16B quarter within 64B row

  f32x4 acc[4][4];
#pragma unroll
  for (int i = 0; i < 4; i++)
#pragma unroll
    for (int j = 0; j < 4; j++) acc[i][j] = (f32x4){0.f, 0.f, 0.f, 0.f};

  // invariant source bases for this thread's staging lanes
  const ushort_t* aSrc = wp2 + (size_t)(co0 + wid * 32 + lrow) * KTOT + lq * 8;
  ushort_t* aDst0 = &As[(wid * 32) * 32];
  ushort_t* aDst1 = &As[(wid * 32 + 16) * 32];
  ushort_t* bDst0 = &Bs[(wid * 32) * 32];
  ushort_t* bDst1 = &Bs[(wid * 32 + 16) * 32];

  for (int tap = 0; tap < 9; ++tap) {
    int ky = tap / 3, kx = tap % 3;
    const ushort_t* bSrc =
        xtb + ((size_t)(y + ky) * PROW + kx + wid * 32 + lrow) * CI_PAD + lq * 8;
    const ushort_t* aSrcT = aSrc + tap * CI_PAD;
    for (int ci0 = 0; ci0 < CI_PAD; ci0 += 32) {
      __syncthreads();   // previous iteration's frag reads complete
      gl_lds16(aSrcT + ci0, aDst0);
      gl_lds16(aSrcT + ci0 + (size_t)16 * KTOT, aDst1);
      gl_lds16(bSrc + ci0, bDst0);
      gl_lds16(bSrc + ci0 + (size_t)16 * CI_PAD, bDst1);
      __syncthreads();   // compiler drains vmcnt before barrier
      bf16x8 af[4], bv[4];
#pragma unroll
      for (int t = 0; t < 4; t++)
        af[t] = *(const bf16x8*)&As[(wm + t * 16 + l15) * 32 + kq];
#pragma unroll
      for (int t = 0; t < 4; t++)
        bv[t] = *(const bf16x8*)&Bs[(wn + t * 16 + l15) * 32 + kq];
#pragma unroll
      for (int i = 0; i < 4; i++)
#pragma unroll
        for (int j = 0; j < 4; j++)
          acc[i][j] = __builtin_amdgcn_mfma_f32_16x16x32_bf16(af[i], bv[j],
                                                              acc[i][j], 0, 0, 0);
    }
  }

#pragma unroll
  for (int i = 0; i < 4; i++) {
    int corow = co0 + wm + i * 16 + q * 4;
#pragma unroll
    for (int j = 0; j < 4; j++) {
      int px = wn + j * 16 + l15;
      size_t base = ((size_t)b * COUT + corow) * HW + y * WSZ + px;
#pragma unroll
      for (int r = 0; r < 4; r++)
        Y[base + (size_t)r * HW] = f2b(acc[i][j][r] + bpack[corow + r]);
    }
  }
}

// ---------------------------------------------------------------- depthwise + attention
// Block: one (b, src, head) x (4 rows x 128 cols). Thread: 2 adjacent px.
// LDS tile: 16 ch x 6 rows (halo) x 144 (col c at index 8+c; halo idx 7,136).
__global__ __launch_bounds__(256) void k_attn(
    const bf16* __restrict__ Y, const float* __restrict__ dep_w,
    const float* __restrict__ dep_b, float* __restrict__ att, int B) {
  __shared__ ushort_t tile[16 * 6 * 144];
  int tid = threadIdx.x;
  int sp = blockIdx.y >> 3, n = blockIdx.y & 7;
  int b = blockIdx.z;
  int y0 = blockIdx.x * 4;
  int qch = n * HD;
  int kch = (sp ? 384 : 128) + n * HD;
  int vch = (sp ? 512 : 256) + n * HD;
  const bf16* Yb = Y + (size_t)b * COUT * HW;

  int r = tid >> 6;          // row in tile 0..3
  int c0 = (tid & 63) * 2;   // col 0..126
  int p0 = (y0 + r) * WSZ + c0;

  auto stage = [&](int ch0) {
    for (int i = tid; i < 16 * 6 * 16; i += 256) {
      int ch = i / 96;
      int rem = i - ch * 96;
      int rr = rem >> 4, c8 = rem & 15;
      int yy = y0 - 1 + rr;
      uint4 v = {0u, 0u, 0u, 0u};
      if (yy >= 0 && yy < HSZ)
        v = *(const uint4*)(Yb + (size_t)(ch0 + ch) * HW + yy * WSZ + c8 * 8);
      *(uint4*)&tile[(ch * 6 + rr) * 144 + 8 + c8 * 8] = v;
    }
    for (int i = tid; i < 16 * 6 * 2; i += 256) {
      int ch = i / 12;
      int rem = i - ch * 12;
      int rr = rem >> 1, side = rem & 1;
      tile[(ch * 6 + rr) * 144 + (side ? 136 : 7)] = 0;
    }
  };

  stage(kch);
  __syncthreads();

  float logits[2][9];
#pragma unroll
  for (int a = 0; a < 9; a++) { logits[0][a] = 0.f; logits[1][a] = 0.f; }

#pragma unroll 4
  for (int d = 0; d < 16; d++) {
    float pt[3][4];
#pragma unroll
    for (int ry = 0; ry < 3; ry++)
#pragma unroll
      for (int cc = 0; cc < 4; cc++)
        pt[ry][cc] = u2f(tile[(d * 6 + r + ry) * 144 + 7 + c0 + cc]);
    float q0 = 0.25f * b2f(Yb[(size_t)(qch + d) * HW + p0]);
    float q1 = 0.25f * b2f(Yb[(size_t)(qch + d) * HW + p0 + 1]);
#pragma unroll
    for (int a = 0; a < 9; a++) {
      const float* wr = dep_w + (d * 9 + a) * 9;   // uniform -> s_load
      float bb = dep_b[d * 9 + a];
      float t0 = bb, t1 = bb;
#pragma unroll
      for (int ky = 0; ky < 3; ky++)
#pragma unroll
        for (int kx = 0; kx < 3; kx++) {
          float wv = wr[ky * 3 + kx];
          t0 += wv * pt[ky][kx];
          t1 += wv * pt[ky][kx + 1];
        }
      logits[0][a] += q0 * t0;
      logits[1][a] += q1 * t1;
    }
  }

  float aw[2][9];
#pragma unroll
  for (int px = 0; px < 2; px++) {
    float m = logits[px][0];
#pragma unroll
    for (int a = 1; a < 9; a++) m = fmaxf(m, logits[px][a]);
    float ssum = 0.f;
#pragma unroll
    for (int a = 0; a < 9; a++) { aw[px][a] = __expf(logits[px][a] - m); ssum += aw[px][a]; }
    float inv = 1.f / ssum;
#pragma unroll
    for (int a = 0; a < 9; a++) aw[px][a] *= inv;
  }

  __syncthreads();
  stage(vch);
  __syncthreads();

  float* dst = att + (((size_t)b * 2 + sp) * DIMC + n * HD) * HW;
#pragma unroll 4
  for (int d = 0; d < 16; d++) {
    float pt[3][4];
#pragma unroll
    for (int ry = 0; ry < 3; ry++)
#pragma unroll
      for (int cc = 0; cc < 4; cc++)
        pt[ry][cc] = u2f(tile[(d * 6 + r + ry) * 144 + 7 + c0 + cc]);
    float o0 = 0.f, o1 = 0.f;
#pragma unroll
    for (int a = 0; a < 9; a++) {
      const float* wr = dep_w + (d * 9 + a) * 9;
      float bb = dep_b[d * 9 + a];
      float t0 = bb, t1 = bb;
#pragma unroll
      for (int ky = 0; ky < 3; ky++)
#pragma unroll
        for (int kx = 0; kx < 3; kx++) {
          float wv = wr[ky * 3 + kx];
          t0 += wv * pt[ky][kx];
          t1 += wv * pt[ky][kx + 1];
        }
      o0 += aw[0][a] * t0;
      o1 += aw[1][a] * t1;
    }
    float2 ov = {o0, o1};
    *(float2*)&dst[(size_t)d * HW + p0] = ov;
  }
}

// ---------------------------------------------------------------- 1x1 proj
__global__ __launch_bounds__(256) void k_proj(
    const float* __restrict__ att, const float* __restrict__ w_pan,
    const float* __restrict__ b_pan, const float* __restrict__ w_ms,
    const float* __restrict__ b_ms, float* __restrict__ out, int B) {
  __shared__ float a_t[128][16];
  int p0 = blockIdx.x * 16;
  int bs = blockIdx.y;
  int b = bs >> 1, sp = bs & 1;
  const float* w = sp ? w_ms : w_pan;
  const float* bias = sp ? b_ms : b_pan;
  const float* src = att + ((size_t)b * 2 + sp) * DIMC * HW;
  for (int i = threadIdx.x; i < 128 * 16; i += 256) {
    int ci = i >> 4, px = i & 15;
    a_t[ci][px] = src[(size_t)ci * HW + p0 + px];
  }
  __syncthreads();
  int co = threadIdx.x & 127;
  int pg = threadIdx.x >> 7;
  float bv = bias[co];
  float acc[8];
#pragma unroll
  for (int j = 0; j < 8; j++) acc[j] = bv;
  for (int ci = 0; ci < 128; ci++) {
    float wv = w[co * 128 + ci];
#pragma unroll
    for (int j = 0; j < 8; j++) acc[j] += wv * a_t[ci][pg * 8 + j];
  }
  float* dst = out + (size_t)sp * B * DIMC * HW + (size_t)b * DIMC * HW +
               (size_t)co * HW + p0 + pg * 8;
#pragma unroll
  for (int j = 0; j < 8; j++) dst[j] = acc[j];
}

// ---------------------------------------------------------------- launch
extern "C" void kernel_launch(void* const* d_in, const int* in_sizes, int n_in,
                              void* d_out, int out_size, void* d_ws, size_t ws_size,
                              hipStream_t stream) {
  const float* x = (const float*)d_in[0];
  const float* ms = (const float*)d_in[1];
  const float* lpan = (const float*)d_in[2];
  const float* pan = (const float*)d_in[3];
  const float* s = (const float*)d_in[4];
  const float* q_w = (const float*)d_in[5];
  const float* q_b = (const float*)d_in[6];
  const float* k_pan_w = (const float*)d_in[7];
  const float* k_pan_b = (const float*)d_in[8];
  const float* v_pan_w = (const float*)d_in[9];
  const float* v_pan_b = (const float*)d_in[10];
  const float* kv_ms_w = (const float*)d_in[11];
  const float* kv_ms_b = (const float*)d_in[12];
  const float* dep_w = (const float*)d_in[13];
  const float* dep_b = (const float*)d_in[14];
  const float* pp_w = (const float*)d_in[15];
  const float* pp_b = (const float*)d_in[16];
  const float* pm_w = (const float*)d_in[17];
  const float* pm_b = (const float*)d_in[18];
  int B = in_sizes[0] / (DIMC * HW);

  char* ws = (char*)d_ws;
  size_t off = 0;
  auto alloc = [&](size_t bytes) -> void* {
    void* pptr = ws + off;
    off = (off + bytes + 255) & ~(size_t)255;
    return pptr;
  };
  ushort_t* wp2 = (ushort_t*)alloc((size_t)COUT * KTOT * sizeof(ushort_t));
  float* bpack = (float*)alloc((size_t)COUT * sizeof(float));
  bf16* Y = (bf16*)alloc((size_t)B * COUT * HW * sizeof(bf16));
  // X_T and att share the tail region: X_T dead after k_conv, att written after.
  ushort_t* xt = (ushort_t*)(ws + off);
  float* att = (float*)(ws + off);
  (void)ws_size; (void)n_in; (void)out_size;

  k_prep<<<dim3((B * NPIX * 20 + 255) / 256), 256, 0, stream>>>(
      x, ms, lpan, pan, s, xt, B);
  k_pack<<<dim3((COUT * KTOT + 255) / 256), 256, 0, stream>>>(
      q_w, q_b, k_pan_w, k_pan_b, v_pan_w, v_pan_b, kv_ms_w, kv_ms_b, wp2, bpack);
  k_conv_mfma<<<dim3(HSZ, COUT / 128, B), 256, 0, stream>>>(xt, wp2, bpack, Y, B);
  k_attn<<<dim3(HSZ / 4, 2 * NH, B), 256, 0, stream>>>(Y, dep_w, dep_b, att, B);
  k_proj<<<dim3(HW / 16, 2 * B), 256, 0, stream>>>(att, pp_w, pp_b, pm_w, pm_b,
                                                   (float*)d_out, B);
}

// Round 6
// 362.665 us; speedup vs baseline: 3.5866x; 1.0212x over previous
//
#include <hip/hip_runtime.h>
#include <hip/hip_bf16.h>

typedef __hip_bfloat16 bf16;
typedef unsigned short ushort_t;
typedef __attribute__((ext_vector_type(8))) __bf16 bf16x8;
typedef __attribute__((ext_vector_type(4))) float f32x4;

#define DIMC 128
#define NH 8
#define HD 16
#define HSZ 128
#define WSZ 128
#define HW (HSZ*WSZ)
#define CI_PAD 160    // 147 real ext channels, padded to 160 (mult of 32)
#define KTOT (9*CI_PAD)   // 1440
#define COUT 640      // 128 q | 128 k_pan | 128 v_pan | 128 k_ms | 128 v_ms
#define PROW 130      // padded image dim (1 halo each side)
#define NPIX (PROW*PROW)

static __device__ __forceinline__ float b2f(bf16 v) { return __bfloat162float(v); }
static __device__ __forceinline__ bf16 f2b(float v) { return __float2bfloat16(v); }
static __device__ __forceinline__ ushort_t f2bu(float v) {
  bf16 t = __float2bfloat16(v);
  return *reinterpret_cast<ushort_t*>(&t);
}
static __device__ __forceinline__ float u2f(ushort_t u) {
  unsigned int w = ((unsigned int)u) << 16;
  float f;
  __builtin_memcpy(&f, &w, 4);
  return f;
}
// async global->LDS, 16B per lane; LDS dest = wave-uniform base + lane*16
static __device__ __forceinline__ void gl_lds16(const void* g, void* l) {
  __builtin_amdgcn_global_load_lds(
      (const __attribute__((address_space(1))) unsigned int*)g,
      (__attribute__((address_space(3))) unsigned int*)l, 16, 0, 0);
}

// ---------------------------------------------------------------- prep X_T (coalesced)
// X_T[b][yy*130+xx][ci] bf16; borders + ci>=147 pre-zeroed by memset.
// Block: one (b, interior row y, 64-px chunk). lane = px, wave = channel group.
__global__ __launch_bounds__(256) void k_prep(
    const float* __restrict__ x, const float* __restrict__ ms,
    const float* __restrict__ lpan, const float* __restrict__ pan,
    const float* __restrict__ s, ushort_t* __restrict__ xt, int B) {
  int t = threadIdx.x;
  int l = t & 63;          // pixel within chunk
  int cg = t >> 6;         // channel group 0..3 (wave-uniform)
  int chunk = blockIdx.x;  // 0..1
  int y = blockIdx.y;      // interior row 0..127
  int b = blockIdx.z;
  int p = y * WSZ + chunk * 64 + l;
  const float* xb = x + (size_t)b * 128 * HW;
  const float* msb = ms + (size_t)b * 8 * HW;

  float vals[40];
  if (cg < 3) {
    int ci0 = cg * 40;
#pragma unroll
    for (int k = 0; k < 40; k++) vals[k] = xb[(size_t)(ci0 + k) * HW + p];
  } else {  // ci 120..159
    float sv = s[b];
#pragma unroll
    for (int k = 0; k < 8; k++) vals[k] = xb[(size_t)(120 + k) * HW + p];
    float lp = lpan[(size_t)b * HW + p];
    float pn = pan[(size_t)b * HW + p];
#pragma unroll
    for (int k = 0; k < 8; k++)
      vals[8 + k] = lp * (1.f - sv) + msb[(size_t)k * HW + p] * sv;  // cond 128..135
    vals[16] = lp;        // 136
    vals[17] = pn;        // 137
    vals[18] = pn - lp;   // 138
#pragma unroll
    for (int k = 0; k < 8; k++) vals[19 + k] = msb[(size_t)k * HW + p];  // 139..146
#pragma unroll
    for (int k = 27; k < 40; k++) vals[k] = 0.f;  // 147..159
  }
  ushort_t us[40];
#pragma unroll
  for (int k = 0; k < 40; k++) us[k] = f2bu(vals[k]);
  int yy = y + 1, xx = 1 + chunk * 64 + l;
  ushort_t* dst = xt + ((size_t)b * NPIX + (size_t)yy * PROW + xx) * CI_PAD + cg * 40;
#pragma unroll
  for (int k = 0; k < 5; k++) *(uint4*)(dst + k * 8) = *(uint4*)(us + k * 8);
}

// ---------------------------------------------------------------- pack weights (coalesced)
// wp2[co][tap*160+ci]; thread per (co,ci) reads 9 contiguous taps.
__global__ __launch_bounds__(256) void k_pack(
    const float* __restrict__ qw, const float* __restrict__ qb,
    const float* __restrict__ kpw, const float* __restrict__ kpb,
    const float* __restrict__ vpw, const float* __restrict__ vpb,
    const float* __restrict__ kvw, const float* __restrict__ kvb,
    ushort_t* __restrict__ wp2, float* __restrict__ bpack) {
  int g = blockIdx.x * 256 + threadIdx.x;
  if (g < COUT * CI_PAD) {
    int co = g / CI_PAD, ci = g % CI_PAD;
    const float* src = nullptr;
    if (ci < 147) {
      if (co < 128) {
        if (ci < 136) src = qw + ((size_t)co * 136 + ci) * 9;
      } else if (co < 256) {
        int o = co - 128;
        if (ci < 128) src = kpw + ((size_t)o * 129 + ci) * 9;
        else if (ci == 136) src = kpw + ((size_t)o * 129 + 128) * 9;
      } else if (co < 384) {
        int o = co - 256;
        if (ci < 128) src = vpw + ((size_t)o * 131 + ci) * 9;
        else if (ci >= 136 && ci <= 138) src = vpw + ((size_t)o * 131 + 128 + (ci - 136)) * 9;
      } else {
        int o = co - 384;
        if (ci < 128) src = kvw + ((size_t)o * 136 + ci) * 9;
        else if (ci >= 139) src = kvw + ((size_t)o * 136 + 128 + (ci - 139)) * 9;
      }
    }
    ushort_t* d = wp2 + (size_t)co * KTOT + ci;
#pragma unroll
    for (int tp = 0; tp < 9; tp++) d[(size_t)tp * CI_PAD] = f2bu(src ? src[tp] : 0.f);
  }
  if (g < COUT) {
    float bv;
    if (g < 128) bv = qb[g];
    else if (g < 256) bv = kpb[g - 128];
    else if (g < 384) bv = vpb[g - 256];
    else bv = kvb[g - 384];
    bpack[g] = bv;
  }
}

// ---------------------------------------------------------------- MFMA implicit GEMM conv
// C[co][px] = sum_{tap,ci} W[co][tap*160+ci] * X_T[(y+ky)*130 + px + kx][ci]
// Block: 128 co x 128 px (one image row); 4 waves 2x2; 64x64/wave; BK=32.
// Staging via global_load_lds width 16 (m97 structure).
__global__ __launch_bounds__(256) void k_conv_mfma(
    const ushort_t* __restrict__ xt, const ushort_t* __restrict__ wp2,
    const float* __restrict__ bpack, bf16* __restrict__ Y, int B) {
  __shared__ ushort_t As[128 * 32];   // [co][k]
  __shared__ ushort_t Bs[128 * 32];   // [px][k]
  int tid = threadIdx.x;
  int lane = tid & 63;
  int wid = tid >> 6;
  int y = blockIdx.x;              // image row
  int co0 = blockIdx.y * 128;
  int b = blockIdx.z;
  const ushort_t* xtb = xt + (size_t)b * NPIX * CI_PAD;

  int wm = (wid >> 1) * 64, wn = (wid & 1) * 64;
  int l15 = lane & 15, q = lane >> 4, kq = q * 8;
  int lrow = lane >> 2;            // 0..15: row within 16-row staging group
  int lq = lane & 3;               // 0..3: 16B quarter within 64B row

  f32x4 acc[4][4];
#pragma unroll
  for (int i = 0; i < 4; i++)
#pragma unroll
    for (int j = 0; j < 4; j++) acc[i][j] = (f32x4){0.f, 0.f, 0.f, 0.f};

  // invariant source bases for this thread's staging lanes
  const ushort_t* aSrc = wp2 + (size_t)(co0 + wid * 32 + lrow) * KTOT + lq * 8;
  ushort_t* aDst0 = &As[(wid * 32) * 32];
  ushort_t* aDst1 = &As[(wid * 32 + 16) * 32];
  ushort_t* bDst0 = &Bs[(wid * 32) * 32];
  ushort_t* bDst1 = &Bs[(wid * 32 + 16) * 32];

  for (int tap = 0; tap < 9; ++tap) {
    int ky = tap / 3, kx = tap % 3;
    const ushort_t* bSrc =
        xtb + ((size_t)(y + ky) * PROW + kx + wid * 32 + lrow) * CI_PAD + lq * 8;
    const ushort_t* aSrcT = aSrc + tap * CI_PAD;
    for (int ci0 = 0; ci0 < CI_PAD; ci0 += 32) {
      __syncthreads();   // previous iteration's frag reads complete
      gl_lds16(aSrcT + ci0, aDst0);
      gl_lds16(aSrcT + ci0 + (size_t)16 * KTOT, aDst1);
      gl_lds16(bSrc + ci0, bDst0);
      gl_lds16(bSrc + ci0 + (size_t)16 * CI_PAD, bDst1);
      __syncthreads();   // compiler drains vmcnt before barrier
      bf16x8 af[4], bv[4];
#pragma unroll
      for (int t = 0; t < 4; t++)
        af[t] = *(const bf16x8*)&As[(wm + t * 16 + l15) * 32 + kq];
#pragma unroll
      for (int t = 0; t < 4; t++)
        bv[t] = *(const bf16x8*)&Bs[(wn + t * 16 + l15) * 32 + kq];
#pragma unroll
      for (int i = 0; i < 4; i++)
#pragma unroll
        for (int j = 0; j < 4; j++)
          acc[i][j] = __builtin_amdgcn_mfma_f32_16x16x32_bf16(af[i], bv[j],
                                                              acc[i][j], 0, 0, 0);
    }
  }

#pragma unroll
  for (int i = 0; i < 4; i++) {
    int corow = co0 + wm + i * 16 + q * 4;
#pragma unroll
    for (int j = 0; j < 4; j++) {
      int px = wn + j * 16 + l15;
      size_t base = ((size_t)b * COUT + corow) * HW + y * WSZ + px;
#pragma unroll
      for (int r = 0; r < 4; r++)
        Y[base + (size_t)r * HW] = f2b(acc[i][j][r] + bpack[corow + r]);
    }
  }
}

// ---------------------------------------------------------------- depthwise + attention
// Block: one (b, src, head) x (4 rows x 128 cols). Thread: 2 adjacent px.
// LDS tile: 16 ch x 6 rows (halo) x 144 (col c at index 8+c; halo idx 7,136).
__global__ __launch_bounds__(256) void k_attn(
    const bf16* __restrict__ Y, const float* __restrict__ dep_w,
    const float* __restrict__ dep_b, float* __restrict__ att, int B) {
  __shared__ ushort_t tile[16 * 6 * 144];
  int tid = threadIdx.x;
  int sp = blockIdx.y >> 3, n = blockIdx.y & 7;
  int b = blockIdx.z;
  int y0 = blockIdx.x * 4;
  int qch = n * HD;
  int kch = (sp ? 384 : 128) + n * HD;
  int vch = (sp ? 512 : 256) + n * HD;
  const bf16* Yb = Y + (size_t)b * COUT * HW;

  int r = tid >> 6;          // row in tile 0..3
  int c0 = (tid & 63) * 2;   // col 0..126
  int p0 = (y0 + r) * WSZ + c0;

  auto stage = [&](int ch0) {
    for (int i = tid; i < 16 * 6 * 16; i += 256) {
      int ch = i / 96;
      int rem = i - ch * 96;
      int rr = rem >> 4, c8 = rem & 15;
      int yy = y0 - 1 + rr;
      uint4 v = {0u, 0u, 0u, 0u};
      if (yy >= 0 && yy < HSZ)
        v = *(const uint4*)(Yb + (size_t)(ch0 + ch) * HW + yy * WSZ + c8 * 8);
      *(uint4*)&tile[(ch * 6 + rr) * 144 + 8 + c8 * 8] = v;
    }
    for (int i = tid; i < 16 * 6 * 2; i += 256) {
      int ch = i / 12;
      int rem = i - ch * 12;
      int rr = rem >> 1, side = rem & 1;
      tile[(ch * 6 + rr) * 144 + (side ? 136 : 7)] = 0;
    }
  };

  stage(kch);
  __syncthreads();

  float logits[2][9];
#pragma unroll
  for (int a = 0; a < 9; a++) { logits[0][a] = 0.f; logits[1][a] = 0.f; }

#pragma unroll 4
  for (int d = 0; d < 16; d++) {
    float pt[3][4];
#pragma unroll
    for (int ry = 0; ry < 3; ry++)
#pragma unroll
      for (int cc = 0; cc < 4; cc++)
        pt[ry][cc] = u2f(tile[(d * 6 + r + ry) * 144 + 7 + c0 + cc]);
    float q0 = 0.25f * b2f(Yb[(size_t)(qch + d) * HW + p0]);
    float q1 = 0.25f * b2f(Yb[(size_t)(qch + d) * HW + p0 + 1]);
#pragma unroll
    for (int a = 0; a < 9; a++) {
      const float* wr = dep_w + (d * 9 + a) * 9;   // uniform -> s_load
      float bb = dep_b[d * 9 + a];
      float t0 = bb, t1 = bb;
#pragma unroll
      for (int ky = 0; ky < 3; ky++)
#pragma unroll
        for (int kx = 0; kx < 3; kx++) {
          float wv = wr[ky * 3 + kx];
          t0 += wv * pt[ky][kx];
          t1 += wv * pt[ky][kx + 1];
        }
      logits[0][a] += q0 * t0;
      logits[1][a] += q1 * t1;
    }
  }

  float aw[2][9];
#pragma unroll
  for (int px = 0; px < 2; px++) {
    float m = logits[px][0];
#pragma unroll
    for (int a = 1; a < 9; a++) m = fmaxf(m, logits[px][a]);
    float ssum = 0.f;
#pragma unroll
    for (int a = 0; a < 9; a++) { aw[px][a] = __expf(logits[px][a] - m); ssum += aw[px][a]; }
    float inv = 1.f / ssum;
#pragma unroll
    for (int a = 0; a < 9; a++) aw[px][a] *= inv;
  }

  __syncthreads();
  stage(vch);
  __syncthreads();

  float* dst = att + (((size_t)b * 2 + sp) * DIMC + n * HD) * HW;
#pragma unroll 4
  for (int d = 0; d < 16; d++) {
    float pt[3][4];
#pragma unroll
    for (int ry = 0; ry < 3; ry++)
#pragma unroll
      for (int cc = 0; cc < 4; cc++)
        pt[ry][cc] = u2f(tile[(d * 6 + r + ry) * 144 + 7 + c0 + cc]);
    float o0 = 0.f, o1 = 0.f;
#pragma unroll
    for (int a = 0; a < 9; a++) {
      const float* wr = dep_w + (d * 9 + a) * 9;
      float bb = dep_b[d * 9 + a];
      float t0 = bb, t1 = bb;
#pragma unroll
      for (int ky = 0; ky < 3; ky++)
#pragma unroll
        for (int kx = 0; kx < 3; kx++) {
          float wv = wr[ky * 3 + kx];
          t0 += wv * pt[ky][kx];
          t1 += wv * pt[ky][kx + 1];
        }
      o0 += aw[0][a] * t0;
      o1 += aw[1][a] * t1;
    }
    float2 ov = {o0, o1};
    *(float2*)&dst[(size_t)d * HW + p0] = ov;
  }
}

// ---------------------------------------------------------------- 1x1 proj
__global__ __launch_bounds__(256) void k_proj(
    const float* __restrict__ att, const float* __restrict__ w_pan,
    const float* __restrict__ b_pan, const float* __restrict__ w_ms,
    const float* __restrict__ b_ms, float* __restrict__ out, int B) {
  __shared__ float a_t[128][16];
  int p0 = blockIdx.x * 16;
  int bs = blockIdx.y;
  int b = bs >> 1, sp = bs & 1;
  const float* w = sp ? w_ms : w_pan;
  const float* bias = sp ? b_ms : b_pan;
  const float* src = att + ((size_t)b * 2 + sp) * DIMC * HW;
  for (int i = threadIdx.x; i < 128 * 16; i += 256) {
    int ci = i >> 4, px = i & 15;
    a_t[ci][px] = src[(size_t)ci * HW + p0 + px];
  }
  __syncthreads();
  int co = threadIdx.x & 127;
  int pg = threadIdx.x >> 7;
  float bv = bias[co];
  float acc[8];
#pragma unroll
  for (int j = 0; j < 8; j++) acc[j] = bv;
  for (int ci = 0; ci < 128; ci++) {
    float wv = w[co * 128 + ci];
#pragma unroll
    for (int j = 0; j < 8; j++) acc[j] += wv * a_t[ci][pg * 8 + j];
  }
  float* dst = out + (size_t)sp * B * DIMC * HW + (size_t)b * DIMC * HW +
               (size_t)co * HW + p0 + pg * 8;
#pragma unroll
  for (int j = 0; j < 8; j++) dst[j] = acc[j];
}

// ---------------------------------------------------------------- launch
extern "C" void kernel_launch(void* const* d_in, const int* in_sizes, int n_in,
                              void* d_out, int out_size, void* d_ws, size_t ws_size,
                              hipStream_t stream) {
  const float* x = (const float*)d_in[0];
  const float* ms = (const float*)d_in[1];
  const float* lpan = (const float*)d_in[2];
  const float* pan = (const float*)d_in[3];
  const float* s = (const float*)d_in[4];
  const float* q_w = (const float*)d_in[5];
  const float* q_b = (const float*)d_in[6];
  const float* k_pan_w = (const float*)d_in[7];
  const float* k_pan_b = (const float*)d_in[8];
  const float* v_pan_w = (const float*)d_in[9];
  const float* v_pan_b = (const float*)d_in[10];
  const float* kv_ms_w = (const float*)d_in[11];
  const float* kv_ms_b = (const float*)d_in[12];
  const float* dep_w = (const float*)d_in[13];
  const float* dep_b = (const float*)d_in[14];
  const float* pp_w = (const float*)d_in[15];
  const float* pp_b = (const float*)d_in[16];
  const float* pm_w = (const float*)d_in[17];
  const float* pm_b = (const float*)d_in[18];
  int B = in_sizes[0] / (DIMC * HW);

  char* ws = (char*)d_ws;
  size_t off = 0;
  auto alloc = [&](size_t bytes) -> void* {
    void* pptr = ws + off;
    off = (off + bytes + 255) & ~(size_t)255;
    return pptr;
  };
  ushort_t* wp2 = (ushort_t*)alloc((size_t)COUT * KTOT * sizeof(ushort_t));
  float* bpack = (float*)alloc((size_t)COUT * sizeof(float));
  bf16* Y = (bf16*)alloc((size_t)B * COUT * HW * sizeof(bf16));
  // X_T and att share the tail region: X_T dead after k_conv, att written after.
  ushort_t* xt = (ushort_t*)(ws + off);
  float* att = (float*)(ws + off);
  (void)ws_size; (void)n_in; (void)out_size;

  hipMemsetAsync(xt, 0, (size_t)B * NPIX * CI_PAD * sizeof(ushort_t), stream);
  k_prep<<<dim3(2, HSZ, B), 256, 0, stream>>>(x, ms, lpan, pan, s, xt, B);
  k_pack<<<dim3((COUT * CI_PAD + 255) / 256), 256, 0, stream>>>(
      q_w, q_b, k_pan_w, k_pan_b, v_pan_w, v_pan_b, kv_ms_w, kv_ms_b, wp2, bpack);
  k_conv_mfma<<<dim3(HSZ, COUT / 128, B), 256, 0, stream>>>(xt, wp2, bpack, Y, B);
  k_attn<<<dim3(HSZ / 4, 2 * NH, B), 256, 0, stream>>>(Y, dep_w, dep_b, att, B);
  k_proj<<<dim3(HW / 16, 2 * B), 256, 0, stream>>>(att, pp_w, pp_b, pm_w, pm_b,
                                                   (float*)d_out, B);
}

// Round 7
// 300.962 us; speedup vs baseline: 4.3219x; 1.2050x over previous
//
#include <hip/hip_runtime.h>
#include <hip/hip_bf16.h>

typedef __hip_bfloat16 bf16;
typedef unsigned short ushort_t;
typedef __attribute__((ext_vector_type(8))) __bf16 bf16x8;
typedef __attribute__((ext_vector_type(4))) float f32x4;

#define DIMC 128
#define NH 8
#define HD 16
#define HSZ 128
#define WSZ 128
#define HW (HSZ*WSZ)
#define CI_PAD 160    // 147 real ext channels, padded to 160 (mult of 32)
#define KTOT (9*CI_PAD)   // 1440
#define COUT 640      // 128 q | 128 k_pan | 128 v_pan | 128 k_ms | 128 v_ms
#define PROW 130      // padded image dim (1 halo each side)
#define NPIX (PROW*PROW)

static __device__ __forceinline__ float b2f(bf16 v) { return __bfloat162float(v); }
static __device__ __forceinline__ bf16 f2b(float v) { return __float2bfloat16(v); }
static __device__ __forceinline__ ushort_t f2bu(float v) {
  bf16 t = __float2bfloat16(v);
  return *reinterpret_cast<ushort_t*>(&t);
}
static __device__ __forceinline__ float u2f(ushort_t u) {
  unsigned int w = ((unsigned int)u) << 16;
  float f;
  __builtin_memcpy(&f, &w, 4);
  return f;
}
// async global->LDS, 16B per lane; LDS dest = wave-uniform base + lane*16
static __device__ __forceinline__ void gl_lds16(const void* g, void* l) {
  __builtin_amdgcn_global_load_lds(
      (const __attribute__((address_space(1))) unsigned int*)g,
      (__attribute__((address_space(3))) unsigned int*)l, 16, 0, 0);
}

// ---------------------------------------------------------------- prep X_T (coalesced)
__global__ __launch_bounds__(256) void k_prep(
    const float* __restrict__ x, const float* __restrict__ ms,
    const float* __restrict__ lpan, const float* __restrict__ pan,
    const float* __restrict__ s, ushort_t* __restrict__ xt, int B) {
  int t = threadIdx.x;
  int l = t & 63;          // pixel within chunk
  int cg = t >> 6;         // channel group 0..3 (wave-uniform)
  int chunk = blockIdx.x;  // 0..1
  int y = blockIdx.y;      // interior row 0..127
  int b = blockIdx.z;
  int p = y * WSZ + chunk * 64 + l;
  const float* xb = x + (size_t)b * 128 * HW;
  const float* msb = ms + (size_t)b * 8 * HW;

  float vals[40];
  if (cg < 3) {
    int ci0 = cg * 40;
#pragma unroll
    for (int k = 0; k < 40; k++) vals[k] = xb[(size_t)(ci0 + k) * HW + p];
  } else {  // ci 120..159
    float sv = s[b];
#pragma unroll
    for (int k = 0; k < 8; k++) vals[k] = xb[(size_t)(120 + k) * HW + p];
    float lp = lpan[(size_t)b * HW + p];
    float pn = pan[(size_t)b * HW + p];
#pragma unroll
    for (int k = 0; k < 8; k++)
      vals[8 + k] = lp * (1.f - sv) + msb[(size_t)k * HW + p] * sv;  // cond
    vals[16] = lp;
    vals[17] = pn;
    vals[18] = pn - lp;
#pragma unroll
    for (int k = 0; k < 8; k++) vals[19 + k] = msb[(size_t)k * HW + p];
#pragma unroll
    for (int k = 27; k < 40; k++) vals[k] = 0.f;
  }
  ushort_t us[40];
#pragma unroll
  for (int k = 0; k < 40; k++) us[k] = f2bu(vals[k]);
  int yy = y + 1, xx = 1 + chunk * 64 + l;
  ushort_t* dst = xt + ((size_t)b * NPIX + (size_t)yy * PROW + xx) * CI_PAD + cg * 40;
#pragma unroll
  for (int k = 0; k < 5; k++) *(uint4*)(dst + k * 8) = *(uint4*)(us + k * 8);
}

// ---------------------------------------------------------------- pack weights (coalesced)
// wp2[co][tap*160+ci] + wproj[sp*128+co][ci] + bpack[0..639 conv | 640..895 proj]
__global__ __launch_bounds__(256) void k_pack(
    const float* __restrict__ qw, const float* __restrict__ qb,
    const float* __restrict__ kpw, const float* __restrict__ kpb,
    const float* __restrict__ vpw, const float* __restrict__ vpb,
    const float* __restrict__ kvw, const float* __restrict__ kvb,
    const float* __restrict__ ppw, const float* __restrict__ ppb,
    const float* __restrict__ pmw, const float* __restrict__ pmb,
    ushort_t* __restrict__ wp2, ushort_t* __restrict__ wproj,
    float* __restrict__ bpack) {
  int g = blockIdx.x * 256 + threadIdx.x;
  if (g < COUT * CI_PAD) {
    int co = g / CI_PAD, ci = g % CI_PAD;
    const float* src = nullptr;
    if (ci < 147) {
      if (co < 128) {
        if (ci < 136) src = qw + ((size_t)co * 136 + ci) * 9;
      } else if (co < 256) {
        int o = co - 128;
        if (ci < 128) src = kpw + ((size_t)o * 129 + ci) * 9;
        else if (ci == 136) src = kpw + ((size_t)o * 129 + 128) * 9;
      } else if (co < 384) {
        int o = co - 256;
        if (ci < 128) src = vpw + ((size_t)o * 131 + ci) * 9;
        else if (ci >= 136 && ci <= 138) src = vpw + ((size_t)o * 131 + 128 + (ci - 136)) * 9;
      } else {
        int o = co - 384;
        if (ci < 128) src = kvw + ((size_t)o * 136 + ci) * 9;
        else if (ci >= 139) src = kvw + ((size_t)o * 136 + 128 + (ci - 139)) * 9;
      }
    }
    ushort_t* d = wp2 + (size_t)co * KTOT + ci;
#pragma unroll
    for (int tp = 0; tp < 9; tp++) d[(size_t)tp * CI_PAD] = f2bu(src ? src[tp] : 0.f);
  }
  if (g < 2 * 128 * 128) {   // proj weights
    int sp = g >> 14;
    int rem = g & 16383;
    wproj[g] = f2bu(sp ? pmw[rem] : ppw[rem]);
  }
  if (g < COUT) {
    float bv;
    if (g < 128) bv = qb[g];
    else if (g < 256) bv = kpb[g - 128];
    else if (g < 384) bv = vpb[g - 256];
    else bv = kvb[g - 384];
    bpack[g] = bv;
  } else if (g < COUT + 256) {
    int o = g - COUT;
    bpack[g] = (o < 128) ? ppb[o] : pmb[o - 128];
  }
}

// ---------------------------------------------------------------- MFMA implicit GEMM conv
__global__ __launch_bounds__(256) void k_conv_mfma(
    const ushort_t* __restrict__ xt, const ushort_t* __restrict__ wp2,
    const float* __restrict__ bpack, bf16* __restrict__ Y, int B) {
  __shared__ ushort_t As[128 * 32];   // [co][k]
  __shared__ ushort_t Bs[128 * 32];   // [px][k]
  int tid = threadIdx.x;
  int lane = tid & 63;
  int wid = tid >> 6;
  int y = blockIdx.x;              // image row
  int co0 = blockIdx.y * 128;
  int b = blockIdx.z;
  const ushort_t* xtb = xt + (size_t)b * NPIX * CI_PAD;

  int wm = (wid >> 1) * 64, wn = (wid & 1) * 64;
  int l15 = lane & 15, q = lane >> 4, kq = q * 8;
  int lrow = lane >> 2;
  int lq = lane & 3;

  f32x4 acc[4][4];
#pragma unroll
  for (int i = 0; i < 4; i++)
#pragma unroll
    for (int j = 0; j < 4; j++) acc[i][j] = (f32x4){0.f, 0.f, 0.f, 0.f};

  const ushort_t* aSrc = wp2 + (size_t)(co0 + wid * 32 + lrow) * KTOT + lq * 8;
  ushort_t* aDst0 = &As[(wid * 32) * 32];
  ushort_t* aDst1 = &As[(wid * 32 + 16) * 32];
  ushort_t* bDst0 = &Bs[(wid * 32) * 32];
  ushort_t* bDst1 = &Bs[(wid * 32 + 16) * 32];

  for (int tap = 0; tap < 9; ++tap) {
    int ky = tap / 3, kx = tap % 3;
    const ushort_t* bSrc =
        xtb + ((size_t)(y + ky) * PROW + kx + wid * 32 + lrow) * CI_PAD + lq * 8;
    const ushort_t* aSrcT = aSrc + tap * CI_PAD;
    for (int ci0 = 0; ci0 < CI_PAD; ci0 += 32) {
      __syncthreads();
      gl_lds16(aSrcT + ci0, aDst0);
      gl_lds16(aSrcT + ci0 + (size_t)16 * KTOT, aDst1);
      gl_lds16(bSrc + ci0, bDst0);
      gl_lds16(bSrc + ci0 + (size_t)16 * CI_PAD, bDst1);
      __syncthreads();
      bf16x8 af[4], bv[4];
#pragma unroll
      for (int t = 0; t < 4; t++)
        af[t] = *(const bf16x8*)&As[(wm + t * 16 + l15) * 32 + kq];
#pragma unroll
      for (int t = 0; t < 4; t++)
        bv[t] = *(const bf16x8*)&Bs[(wn + t * 16 + l15) * 32 + kq];
#pragma unroll
      for (int i = 0; i < 4; i++)
#pragma unroll
        for (int j = 0; j < 4; j++)
          acc[i][j] = __builtin_amdgcn_mfma_f32_16x16x32_bf16(af[i], bv[j],
                                                              acc[i][j], 0, 0, 0);
    }
  }

#pragma unroll
  for (int i = 0; i < 4; i++) {
    int corow = co0 + wm + i * 16 + q * 4;
#pragma unroll
    for (int j = 0; j < 4; j++) {
      int px = wn + j * 16 + l15;
      size_t base = ((size_t)b * COUT + corow) * HW + y * WSZ + px;
#pragma unroll
      for (int r = 0; r < 4; r++)
        Y[base + (size_t)r * HW] = f2b(acc[i][j][r] + bpack[corow + r]);
    }
  }
}

// ---------------------------------------------------------------- depthwise + attention
// Output: att_t[( (b*2+sp)*HW + px )*128 + n*16+d]  bf16 (transposed for proj MFMA)
__global__ __launch_bounds__(256) void k_attn(
    const bf16* __restrict__ Y, const float* __restrict__ dep_w,
    const float* __restrict__ dep_b, ushort_t* __restrict__ att_t, int B) {
  __shared__ ushort_t tile[16 * 6 * 144];
  int tid = threadIdx.x;
  int sp = blockIdx.y >> 3, n = blockIdx.y & 7;
  int b = blockIdx.z;
  int y0 = blockIdx.x * 4;
  int qch = n * HD;
  int kch = (sp ? 384 : 128) + n * HD;
  int vch = (sp ? 512 : 256) + n * HD;
  const bf16* Yb = Y + (size_t)b * COUT * HW;

  int r = tid >> 6;          // row in tile 0..3
  int c0 = (tid & 63) * 2;   // col 0..126
  int p0 = (y0 + r) * WSZ + c0;

  auto stage = [&](int ch0) {
    for (int i = tid; i < 16 * 6 * 16; i += 256) {
      int ch = i / 96;
      int rem = i - ch * 96;
      int rr = rem >> 4, c8 = rem & 15;
      int yy = y0 - 1 + rr;
      uint4 v = {0u, 0u, 0u, 0u};
      if (yy >= 0 && yy < HSZ)
        v = *(const uint4*)(Yb + (size_t)(ch0 + ch) * HW + yy * WSZ + c8 * 8);
      *(uint4*)&tile[(ch * 6 + rr) * 144 + 8 + c8 * 8] = v;
    }
    for (int i = tid; i < 16 * 6 * 2; i += 256) {
      int ch = i / 12;
      int rem = i - ch * 12;
      int rr = rem >> 1, side = rem & 1;
      tile[(ch * 6 + rr) * 144 + (side ? 136 : 7)] = 0;
    }
  };

  stage(kch);
  __syncthreads();

  float logits[2][9];
#pragma unroll
  for (int a = 0; a < 9; a++) { logits[0][a] = 0.f; logits[1][a] = 0.f; }

#pragma unroll 4
  for (int d = 0; d < 16; d++) {
    float pt[3][4];
#pragma unroll
    for (int ry = 0; ry < 3; ry++)
#pragma unroll
      for (int cc = 0; cc < 4; cc++)
        pt[ry][cc] = u2f(tile[(d * 6 + r + ry) * 144 + 7 + c0 + cc]);
    float q0 = 0.25f * b2f(Yb[(size_t)(qch + d) * HW + p0]);
    float q1 = 0.25f * b2f(Yb[(size_t)(qch + d) * HW + p0 + 1]);
#pragma unroll
    for (int a = 0; a < 9; a++) {
      const float* wr = dep_w + (d * 9 + a) * 9;   // uniform -> s_load
      float bb = dep_b[d * 9 + a];
      float t0 = bb, t1 = bb;
#pragma unroll
      for (int ky = 0; ky < 3; ky++)
#pragma unroll
        for (int kx = 0; kx < 3; kx++) {
          float wv = wr[ky * 3 + kx];
          t0 += wv * pt[ky][kx];
          t1 += wv * pt[ky][kx + 1];
        }
      logits[0][a] += q0 * t0;
      logits[1][a] += q1 * t1;
    }
  }

  float aw[2][9];
#pragma unroll
  for (int px = 0; px < 2; px++) {
    float m = logits[px][0];
#pragma unroll
    for (int a = 1; a < 9; a++) m = fmaxf(m, logits[px][a]);
    float ssum = 0.f;
#pragma unroll
    for (int a = 0; a < 9; a++) { aw[px][a] = __expf(logits[px][a] - m); ssum += aw[px][a]; }
    float inv = 1.f / ssum;
#pragma unroll
    for (int a = 0; a < 9; a++) aw[px][a] *= inv;
  }

  __syncthreads();
  stage(vch);
  __syncthreads();

  ushort_t ou[2][16];
#pragma unroll 4
  for (int d = 0; d < 16; d++) {
    float pt[3][4];
#pragma unroll
    for (int ry = 0; ry < 3; ry++)
#pragma unroll
      for (int cc = 0; cc < 4; cc++)
        pt[ry][cc] = u2f(tile[(d * 6 + r + ry) * 144 + 7 + c0 + cc]);
    float o0 = 0.f, o1 = 0.f;
#pragma unroll
    for (int a = 0; a < 9; a++) {
      const float* wr = dep_w + (d * 9 + a) * 9;
      float bb = dep_b[d * 9 + a];
      float t0 = bb, t1 = bb;
#pragma unroll
      for (int ky = 0; ky < 3; ky++)
#pragma unroll
        for (int kx = 0; kx < 3; kx++) {
          float wv = wr[ky * 3 + kx];
          t0 += wv * pt[ky][kx];
          t1 += wv * pt[ky][kx + 1];
        }
      o0 += aw[0][a] * t0;
      o1 += aw[1][a] * t1;
    }
    ou[0][d] = f2bu(o0);
    ou[1][d] = f2bu(o1);
  }
  ushort_t* dst0 = att_t + (((size_t)(b * 2 + sp)) * HW + p0) * 128 + n * 16;
  *(uint4*)(dst0) = *(uint4*)&ou[0][0];
  *(uint4*)(dst0 + 8) = *(uint4*)&ou[0][8];
  *(uint4*)(dst0 + 128) = *(uint4*)&ou[1][0];
  *(uint4*)(dst0 + 136) = *(uint4*)&ou[1][8];
}

// ---------------------------------------------------------------- 1x1 proj as MFMA GEMM
// C[co][px] = sum_ci wproj[sp*128+co][ci] * att_t[bsp*HW+px][ci] + bias
__global__ __launch_bounds__(256) void k_proj_mfma(
    const ushort_t* __restrict__ att_t, const ushort_t* __restrict__ wproj,
    const float* __restrict__ bpack, float* __restrict__ out, int B) {
  __shared__ ushort_t As[128 * 32];   // [co][k]
  __shared__ ushort_t Bs[128 * 32];   // [px][k]
  int tid = threadIdx.x;
  int lane = tid & 63;
  int wid = tid >> 6;
  int px0 = blockIdx.x * 128;
  int bsp = blockIdx.z;            // b*2+sp
  int b = bsp >> 1, sp = bsp & 1;

  int wm = (wid >> 1) * 64, wn = (wid & 1) * 64;
  int l15 = lane & 15, q = lane >> 4, kq = q * 8;
  int lrow = lane >> 2;
  int lq = lane & 3;

  f32x4 acc[4][4];
#pragma unroll
  for (int i = 0; i < 4; i++)
#pragma unroll
    for (int j = 0; j < 4; j++) acc[i][j] = (f32x4){0.f, 0.f, 0.f, 0.f};

  const ushort_t* aSrc = wproj + (size_t)(sp * 128 + wid * 32 + lrow) * 128 + lq * 8;
  const ushort_t* bSrc = att_t + ((size_t)bsp * HW + px0 + wid * 32 + lrow) * 128 + lq * 8;
  ushort_t* aDst0 = &As[(wid * 32) * 32];
  ushort_t* aDst1 = &As[(wid * 32 + 16) * 32];
  ushort_t* bDst0 = &Bs[(wid * 32) * 32];
  ushort_t* bDst1 = &Bs[(wid * 32 + 16) * 32];

  for (int ci0 = 0; ci0 < 128; ci0 += 32) {
    __syncthreads();
    gl_lds16(aSrc + ci0, aDst0);
    gl_lds16(aSrc + ci0 + (size_t)16 * 128, aDst1);
    gl_lds16(bSrc + ci0, bDst0);
    gl_lds16(bSrc + ci0 + (size_t)16 * 128, bDst1);
    __syncthreads();
    bf16x8 af[4], bv[4];
#pragma unroll
    for (int t = 0; t < 4; t++)
      af[t] = *(const bf16x8*)&As[(wm + t * 16 + l15) * 32 + kq];
#pragma unroll
    for (int t = 0; t < 4; t++)
      bv[t] = *(const bf16x8*)&Bs[(wn + t * 16 + l15) * 32 + kq];
#pragma unroll
    for (int i = 0; i < 4; i++)
#pragma unroll
      for (int j = 0; j < 4; j++)
        acc[i][j] = __builtin_amdgcn_mfma_f32_16x16x32_bf16(af[i], bv[j],
                                                            acc[i][j], 0, 0, 0);
  }

  float* ob = out + (size_t)sp * B * DIMC * HW + (size_t)b * DIMC * HW;
#pragma unroll
  for (int i = 0; i < 4; i++) {
    int corow = wm + i * 16 + q * 4;
#pragma unroll
    for (int j = 0; j < 4; j++) {
      int px = px0 + wn + j * 16 + l15;
#pragma unroll
      for (int r = 0; r < 4; r++)
        ob[(size_t)(corow + r) * HW + px] =
            acc[i][j][r] + bpack[640 + sp * 128 + corow + r];
    }
  }
}

// ---------------------------------------------------------------- launch
extern "C" void kernel_launch(void* const* d_in, const int* in_sizes, int n_in,
                              void* d_out, int out_size, void* d_ws, size_t ws_size,
                              hipStream_t stream) {
  const float* x = (const float*)d_in[0];
  const float* ms = (const float*)d_in[1];
  const float* lpan = (const float*)d_in[2];
  const float* pan = (const float*)d_in[3];
  const float* s = (const float*)d_in[4];
  const float* q_w = (const float*)d_in[5];
  const float* q_b = (const float*)d_in[6];
  const float* k_pan_w = (const float*)d_in[7];
  const float* k_pan_b = (const float*)d_in[8];
  const float* v_pan_w = (const float*)d_in[9];
  const float* v_pan_b = (const float*)d_in[10];
  const float* kv_ms_w = (const float*)d_in[11];
  const float* kv_ms_b = (const float*)d_in[12];
  const float* dep_w = (const float*)d_in[13];
  const float* dep_b = (const float*)d_in[14];
  const float* pp_w = (const float*)d_in[15];
  const float* pp_b = (const float*)d_in[16];
  const float* pm_w = (const float*)d_in[17];
  const float* pm_b = (const float*)d_in[18];
  int B = in_sizes[0] / (DIMC * HW);

  char* ws = (char*)d_ws;
  size_t off = 0;
  auto alloc = [&](size_t bytes) -> void* {
    void* pptr = ws + off;
    off = (off + bytes + 255) & ~(size_t)255;
    return pptr;
  };
  ushort_t* wp2 = (ushort_t*)alloc((size_t)COUT * KTOT * sizeof(ushort_t));
  ushort_t* wproj = (ushort_t*)alloc((size_t)2 * 128 * 128 * sizeof(ushort_t));
  float* bpack = (float*)alloc((size_t)(COUT + 256) * sizeof(float));
  bf16* Y = (bf16*)alloc((size_t)B * COUT * HW * sizeof(bf16));
  // X_T and att_t share the tail region: X_T dead after conv, att_t written after.
  size_t xt_sz = (size_t)B * NPIX * CI_PAD * sizeof(ushort_t);
  size_t att_sz = (size_t)B * 2 * HW * 128 * sizeof(ushort_t);
  ushort_t* xt = (ushort_t*)(ws + off);
  ushort_t* att_t = (ushort_t*)(ws + off);
  off += (att_sz > xt_sz ? att_sz : xt_sz);
  (void)ws_size; (void)n_in; (void)out_size;

  hipMemsetAsync(xt, 0, xt_sz, stream);
  k_prep<<<dim3(2, HSZ, B), 256, 0, stream>>>(x, ms, lpan, pan, s, xt, B);
  k_pack<<<dim3((COUT * CI_PAD + 255) / 256), 256, 0, stream>>>(
      q_w, q_b, k_pan_w, k_pan_b, v_pan_w, v_pan_b, kv_ms_w, kv_ms_b,
      pp_w, pp_b, pm_w, pm_b, wp2, wproj, bpack);
  k_conv_mfma<<<dim3(HSZ, COUT / 128, B), 256, 0, stream>>>(xt, wp2, bpack, Y, B);
  k_attn<<<dim3(HSZ / 4, 2 * NH, B), 256, 0, stream>>>(Y, dep_w, dep_b, att_t, B);
  k_proj_mfma<<<dim3(HW / 128, 1, 2 * B), 256, 0, stream>>>(att_t, wproj, bpack,
                                                            (float*)d_out, B);
}

// Round 8
// 262.552 us; speedup vs baseline: 4.9542x; 1.1463x over previous
//
#include <hip/hip_runtime.h>
#include <hip/hip_bf16.h>

typedef __hip_bfloat16 bf16;
typedef unsigned short ushort_t;
typedef __attribute__((ext_vector_type(8))) __bf16 bf16x8;
typedef __attribute__((ext_vector_type(4))) float f32x4;

#define DIMC 128
#define NH 8
#define HD 16
#define HSZ 128
#define WSZ 128
#define HW (HSZ*WSZ)
#define CI_PAD 160    // 147 real ext channels, padded to 160 (mult of 32)
#define KTOT (9*CI_PAD)   // 1440
#define COUT 640      // 128 q | 128 k_pan | 128 v_pan | 128 k_ms | 128 v_ms
#define PROW 130      // padded image dim (1 halo each side)
#define NPIX (PROW*PROW)
#define TW 136        // attn fp32 tile row width; interior col c at idx 4+c

static __device__ __forceinline__ float b2f(bf16 v) { return __bfloat162float(v); }
static __device__ __forceinline__ bf16 f2b(float v) { return __float2bfloat16(v); }
static __device__ __forceinline__ ushort_t f2bu(float v) {
  bf16 t = __float2bfloat16(v);
  return *reinterpret_cast<ushort_t*>(&t);
}
static __device__ __forceinline__ float u2f(unsigned int u) {
  unsigned int w = u << 16;
  float f;
  __builtin_memcpy(&f, &w, 4);
  return f;
}
static __device__ __forceinline__ float u2f_hi(unsigned int u) {
  unsigned int w = u & 0xffff0000u;
  float f;
  __builtin_memcpy(&f, &w, 4);
  return f;
}
// async global->LDS, 16B per lane; LDS dest = wave-uniform base + lane*16
static __device__ __forceinline__ void gl_lds16(const void* g, void* l) {
  __builtin_amdgcn_global_load_lds(
      (const __attribute__((address_space(1))) unsigned int*)g,
      (__attribute__((address_space(3))) unsigned int*)l, 16, 0, 0);
}

// ---------------------------------------------------------------- prep X_T (coalesced)
// y<128: interior row. y==128: zero rows 0/129. y==129: zero cols 0/129.
__global__ __launch_bounds__(256) void k_prep(
    const float* __restrict__ x, const float* __restrict__ ms,
    const float* __restrict__ lpan, const float* __restrict__ pan,
    const float* __restrict__ s, ushort_t* __restrict__ xt, int B) {
  int t = threadIdx.x;
  int y = blockIdx.y;
  int b = blockIdx.z;
  ushort_t* xtb = xt + (size_t)b * NPIX * CI_PAD;
  if (y == 128) {            // border rows: yy = 0 (x=0) or 129 (x=1)
    int yy = blockIdx.x ? 129 : 0;
    uint4 z = {0u, 0u, 0u, 0u};
    uint4* dst = (uint4*)(xtb + (size_t)yy * PROW * CI_PAD);
    for (int i = t; i < PROW * CI_PAD / 8; i += 256) dst[i] = z;
    return;
  }
  if (y == 129) {            // border cols: xx = 0 or 129, yy = 1..128
    int xx = blockIdx.x ? 129 : 0;
    uint4 z = {0u, 0u, 0u, 0u};
    for (int i = t; i < 128 * (CI_PAD / 8); i += 256) {
      int yy = 1 + i / (CI_PAD / 8);
      int q4 = i % (CI_PAD / 8);
      *(uint4*)(xtb + ((size_t)yy * PROW + xx) * CI_PAD + q4 * 8) = z;
    }
    return;
  }
  int l = t & 63;          // pixel within chunk
  int cg = t >> 6;         // channel group 0..3 (wave-uniform)
  int chunk = blockIdx.x;  // 0..1
  int p = y * WSZ + chunk * 64 + l;
  const float* xb = x + (size_t)b * 128 * HW;
  const float* msb = ms + (size_t)b * 8 * HW;

  float vals[40];
  if (cg < 3) {
    int ci0 = cg * 40;
#pragma unroll
    for (int k = 0; k < 40; k++) vals[k] = xb[(size_t)(ci0 + k) * HW + p];
  } else {  // ci 120..159
    float sv = s[b];
#pragma unroll
    for (int k = 0; k < 8; k++) vals[k] = xb[(size_t)(120 + k) * HW + p];
    float lp = lpan[(size_t)b * HW + p];
    float pn = pan[(size_t)b * HW + p];
#pragma unroll
    for (int k = 0; k < 8; k++)
      vals[8 + k] = lp * (1.f - sv) + msb[(size_t)k * HW + p] * sv;  // cond
    vals[16] = lp;
    vals[17] = pn;
    vals[18] = pn - lp;
#pragma unroll
    for (int k = 0; k < 8; k++) vals[19 + k] = msb[(size_t)k * HW + p];
#pragma unroll
    for (int k = 27; k < 40; k++) vals[k] = 0.f;
  }
  ushort_t us[40];
#pragma unroll
  for (int k = 0; k < 40; k++) us[k] = f2bu(vals[k]);
  int yy = y + 1, xx = 1 + chunk * 64 + l;
  ushort_t* dst = xtb + ((size_t)yy * PROW + xx) * CI_PAD + cg * 40;
#pragma unroll
  for (int k = 0; k < 5; k++) *(uint4*)(dst + k * 8) = *(uint4*)(us + k * 8);
}

// ---------------------------------------------------------------- pack weights (coalesced)
__global__ __launch_bounds__(256) void k_pack(
    const float* __restrict__ qw, const float* __restrict__ qb,
    const float* __restrict__ kpw, const float* __restrict__ kpb,
    const float* __restrict__ vpw, const float* __restrict__ vpb,
    const float* __restrict__ kvw, const float* __restrict__ kvb,
    const float* __restrict__ ppw, const float* __restrict__ ppb,
    const float* __restrict__ pmw, const float* __restrict__ pmb,
    ushort_t* __restrict__ wp2, ushort_t* __restrict__ wproj,
    float* __restrict__ bpack) {
  int g = blockIdx.x * 256 + threadIdx.x;
  if (g < COUT * CI_PAD) {
    int co = g / CI_PAD, ci = g % CI_PAD;
    const float* src = nullptr;
    if (ci < 147) {
      if (co < 128) {
        if (ci < 136) src = qw + ((size_t)co * 136 + ci) * 9;
      } else if (co < 256) {
        int o = co - 128;
        if (ci < 128) src = kpw + ((size_t)o * 129 + ci) * 9;
        else if (ci == 136) src = kpw + ((size_t)o * 129 + 128) * 9;
      } else if (co < 384) {
        int o = co - 256;
        if (ci < 128) src = vpw + ((size_t)o * 131 + ci) * 9;
        else if (ci >= 136 && ci <= 138) src = vpw + ((size_t)o * 131 + 128 + (ci - 136)) * 9;
      } else {
        int o = co - 384;
        if (ci < 128) src = kvw + ((size_t)o * 136 + ci) * 9;
        else if (ci >= 139) src = kvw + ((size_t)o * 136 + 128 + (ci - 139)) * 9;
      }
    }
    ushort_t* d = wp2 + (size_t)co * KTOT + ci;
#pragma unroll
    for (int tp = 0; tp < 9; tp++) d[(size_t)tp * CI_PAD] = f2bu(src ? src[tp] : 0.f);
  }
  if (g < 2 * 128 * 128) {   // proj weights
    int sp = g >> 14;
    int rem = g & 16383;
    wproj[g] = f2bu(sp ? pmw[rem] : ppw[rem]);
  }
  if (g < COUT) {
    float bv;
    if (g < 128) bv = qb[g];
    else if (g < 256) bv = kpb[g - 128];
    else if (g < 384) bv = vpb[g - 256];
    else bv = kvb[g - 384];
    bpack[g] = bv;
  } else if (g < COUT + 256) {
    int o = g - COUT;
    bpack[g] = (o < 128) ? ppb[o] : pmb[o - 128];
  }
}

// ---------------------------------------------------------------- MFMA implicit GEMM conv
__global__ __launch_bounds__(256) void k_conv_mfma(
    const ushort_t* __restrict__ xt, const ushort_t* __restrict__ wp2,
    const float* __restrict__ bpack, bf16* __restrict__ Y, int B) {
  __shared__ ushort_t As[128 * 32];   // [co][k]
  __shared__ ushort_t Bs[128 * 32];   // [px][k]
  int tid = threadIdx.x;
  int lane = tid & 63;
  int wid = tid >> 6;
  int y = blockIdx.x;              // image row
  int co0 = blockIdx.y * 128;
  int b = blockIdx.z;
  const ushort_t* xtb = xt + (size_t)b * NPIX * CI_PAD;

  int wm = (wid >> 1) * 64, wn = (wid & 1) * 64;
  int l15 = lane & 15, q = lane >> 4, kq = q * 8;
  int lrow = lane >> 2;
  int lq = lane & 3;

  f32x4 acc[4][4];
#pragma unroll
  for (int i = 0; i < 4; i++)
#pragma unroll
    for (int j = 0; j < 4; j++) acc[i][j] = (f32x4){0.f, 0.f, 0.f, 0.f};

  const ushort_t* aSrc = wp2 + (size_t)(co0 + wid * 32 + lrow) * KTOT + lq * 8;
  ushort_t* aDst0 = &As[(wid * 32) * 32];
  ushort_t* aDst1 = &As[(wid * 32 + 16) * 32];
  ushort_t* bDst0 = &Bs[(wid * 32) * 32];
  ushort_t* bDst1 = &Bs[(wid * 32 + 16) * 32];

  for (int tap = 0; tap < 9; ++tap) {
    int ky = tap / 3, kx = tap % 3;
    const ushort_t* bSrc =
        xtb + ((size_t)(y + ky) * PROW + kx + wid * 32 + lrow) * CI_PAD + lq * 8;
    const ushort_t* aSrcT = aSrc + tap * CI_PAD;
    for (int ci0 = 0; ci0 < CI_PAD; ci0 += 32) {
      __syncthreads();
      gl_lds16(aSrcT + ci0, aDst0);
      gl_lds16(aSrcT + ci0 + (size_t)16 * KTOT, aDst1);
      gl_lds16(bSrc + ci0, bDst0);
      gl_lds16(bSrc + ci0 + (size_t)16 * CI_PAD, bDst1);
      __syncthreads();
      bf16x8 af[4], bv[4];
#pragma unroll
      for (int t = 0; t < 4; t++)
        af[t] = *(const bf16x8*)&As[(wm + t * 16 + l15) * 32 + kq];
#pragma unroll
      for (int t = 0; t < 4; t++)
        bv[t] = *(const bf16x8*)&Bs[(wn + t * 16 + l15) * 32 + kq];
#pragma unroll
      for (int i = 0; i < 4; i++)
#pragma unroll
        for (int j = 0; j < 4; j++)
          acc[i][j] = __builtin_amdgcn_mfma_f32_16x16x32_bf16(af[i], bv[j],
                                                              acc[i][j], 0, 0, 0);
    }
  }

#pragma unroll
  for (int i = 0; i < 4; i++) {
    int corow = co0 + wm + i * 16 + q * 4;
#pragma unroll
    for (int j = 0; j < 4; j++) {
      int px = wn + j * 16 + l15;
      size_t base = ((size_t)b * COUT + corow) * HW + y * WSZ + px;
#pragma unroll
      for (int r = 0; r < 4; r++)
        Y[base + (size_t)r * HW] = f2b(acc[i][j][r] + bpack[corow + r]);
    }
  }
}

// ---------------------------------------------------------------- depthwise + attention
// fp32 LDS tile [16 ch][6 rows][TW=136]; interior col c at idx 4+c, halos 3/132.
// Thread: 2 adjacent px; float2 packed math. Output transposed bf16 for proj.
__global__ __launch_bounds__(256) void k_attn(
    const bf16* __restrict__ Y, const float* __restrict__ dep_w,
    const float* __restrict__ dep_b, ushort_t* __restrict__ att_t, int B) {
  __shared__ float tile[16 * 6 * TW];
  int tid = threadIdx.x;
  int sp = blockIdx.y >> 3, n = blockIdx.y & 7;
  int b = blockIdx.z;
  int y0 = blockIdx.x * 4;
  int qch = n * HD;
  int kch = (sp ? 384 : 128) + n * HD;
  int vch = (sp ? 512 : 256) + n * HD;
  const bf16* Yb = Y + (size_t)b * COUT * HW;

  int r = tid >> 6;          // row in tile 0..3
  int c0 = (tid & 63) * 2;   // col 0..126
  int p0 = (y0 + r) * WSZ + c0;

  auto stage = [&](int ch0) {
    for (int i = tid; i < 16 * 6 * 16; i += 256) {
      int ch = i / 96;
      int rem = i - ch * 96;
      int rr = rem >> 4, c8 = rem & 15;
      int yy = y0 - 1 + rr;
      float4 f0 = {0.f, 0.f, 0.f, 0.f}, f1 = {0.f, 0.f, 0.f, 0.f};
      if (yy >= 0 && yy < HSZ) {
        uint4 v = *(const uint4*)(Yb + (size_t)(ch0 + ch) * HW + yy * WSZ + c8 * 8);
        f0.x = u2f(v.x); f0.y = u2f_hi(v.x);
        f0.z = u2f(v.y); f0.w = u2f_hi(v.y);
        f1.x = u2f(v.z); f1.y = u2f_hi(v.z);
        f1.z = u2f(v.w); f1.w = u2f_hi(v.w);
      }
      float* dst = &tile[(ch * 6 + rr) * TW + 4 + c8 * 8];
      *(float4*)dst = f0;
      *(float4*)(dst + 4) = f1;
    }
    for (int i = tid; i < 16 * 6 * 2; i += 256) {
      int ch = i / 12;
      int rem = i - ch * 12;
      int rr = rem >> 1, side = rem & 1;
      tile[(ch * 6 + rr) * TW + (side ? 132 : 3)] = 0.f;
    }
  };

  stage(kch);
  __syncthreads();

  float2 logits[9];
#pragma unroll
  for (int a = 0; a < 9; a++) logits[a] = {0.f, 0.f};

#pragma unroll 4
  for (int d = 0; d < 16; d++) {
    float pt[3][4];
#pragma unroll
    for (int ry = 0; ry < 3; ry++) {
      const float* rowp = &tile[(d * 6 + r + ry) * TW + 3 + c0];
#pragma unroll
      for (int cc = 0; cc < 4; cc++) pt[ry][cc] = rowp[cc];
    }
    unsigned int qu = *(const unsigned int*)(Yb + (size_t)(qch + d) * HW + p0);
    float2 qv = {0.25f * u2f(qu), 0.25f * u2f_hi(qu)};
#pragma unroll
    for (int a = 0; a < 9; a++) {
      const float* wr = dep_w + (d * 9 + a) * 9;   // uniform -> s_load
      float bb = dep_b[d * 9 + a];
      float2 tt = {bb, bb};
#pragma unroll
      for (int ky = 0; ky < 3; ky++)
#pragma unroll
        for (int kx = 0; kx < 3; kx++) {
          float wv = wr[ky * 3 + kx];
          tt.x += wv * pt[ky][kx];
          tt.y += wv * pt[ky][kx + 1];
        }
      logits[a].x += qv.x * tt.x;
      logits[a].y += qv.y * tt.y;
    }
  }

  float2 aw[9];
  {
    float2 m = logits[0];
#pragma unroll
    for (int a = 1; a < 9; a++) {
      m.x = fmaxf(m.x, logits[a].x);
      m.y = fmaxf(m.y, logits[a].y);
    }
    float2 ssum = {0.f, 0.f};
#pragma unroll
    for (int a = 0; a < 9; a++) {
      aw[a].x = __expf(logits[a].x - m.x);
      aw[a].y = __expf(logits[a].y - m.y);
      ssum.x += aw[a].x; ssum.y += aw[a].y;
    }
    float2 inv = {1.f / ssum.x, 1.f / ssum.y};
#pragma unroll
    for (int a = 0; a < 9; a++) { aw[a].x *= inv.x; aw[a].y *= inv.y; }
  }

  __syncthreads();
  stage(vch);
  __syncthreads();

  ushort_t ou[2][16];
#pragma unroll 4
  for (int d = 0; d < 16; d++) {
    float pt[3][4];
#pragma unroll
    for (int ry = 0; ry < 3; ry++) {
      const float* rowp = &tile[(d * 6 + r + ry) * TW + 3 + c0];
#pragma unroll
      for (int cc = 0; cc < 4; cc++) pt[ry][cc] = rowp[cc];
    }
    float2 o = {0.f, 0.f};
#pragma unroll
    for (int a = 0; a < 9; a++) {
      const float* wr = dep_w + (d * 9 + a) * 9;
      float bb = dep_b[d * 9 + a];
      float2 tt = {bb, bb};
#pragma unroll
      for (int ky = 0; ky < 3; ky++)
#pragma unroll
        for (int kx = 0; kx < 3; kx++) {
          float wv = wr[ky * 3 + kx];
          tt.x += wv * pt[ky][kx];
          tt.y += wv * pt[ky][kx + 1];
        }
      o.x += aw[a].x * tt.x;
      o.y += aw[a].y * tt.y;
    }
    ou[0][d] = f2bu(o.x);
    ou[1][d] = f2bu(o.y);
  }
  ushort_t* dst0 = att_t + (((size_t)(b * 2 + sp)) * HW + p0) * 128 + n * 16;
  *(uint4*)(dst0) = *(uint4*)&ou[0][0];
  *(uint4*)(dst0 + 8) = *(uint4*)&ou[0][8];
  *(uint4*)(dst0 + 128) = *(uint4*)&ou[1][0];
  *(uint4*)(dst0 + 136) = *(uint4*)&ou[1][8];
}

// ---------------------------------------------------------------- 1x1 proj as MFMA GEMM
__global__ __launch_bounds__(256) void k_proj_mfma(
    const ushort_t* __restrict__ att_t, const ushort_t* __restrict__ wproj,
    const float* __restrict__ bpack, float* __restrict__ out, int B) {
  __shared__ ushort_t As[128 * 32];   // [co][k]
  __shared__ ushort_t Bs[128 * 32];   // [px][k]
  int tid = threadIdx.x;
  int lane = tid & 63;
  int wid = tid >> 6;
  int px0 = blockIdx.x * 128;
  int bsp = blockIdx.z;            // b*2+sp
  int b = bsp >> 1, sp = bsp & 1;

  int wm = (wid >> 1) * 64, wn = (wid & 1) * 64;
  int l15 = lane & 15, q = lane >> 4, kq = q * 8;
  int lrow = lane >> 2;
  int lq = lane & 3;

  f32x4 acc[4][4];
#pragma unroll
  for (int i = 0; i < 4; i++)
#pragma unroll
    for (int j = 0; j < 4; j++) acc[i][j] = (f32x4){0.f, 0.f, 0.f, 0.f};

  const ushort_t* aSrc = wproj + (size_t)(sp * 128 + wid * 32 + lrow) * 128 + lq * 8;
  const ushort_t* bSrc = att_t + ((size_t)bsp * HW + px0 + wid * 32 + lrow) * 128 + lq * 8;
  ushort_t* aDst0 = &As[(wid * 32) * 32];
  ushort_t* aDst1 = &As[(wid * 32 + 16) * 32];
  ushort_t* bDst0 = &Bs[(wid * 32) * 32];
  ushort_t* bDst1 = &Bs[(wid * 32 + 16) * 32];

  for (int ci0 = 0; ci0 < 128; ci0 += 32) {
    __syncthreads();
    gl_lds16(aSrc + ci0, aDst0);
    gl_lds16(aSrc + ci0 + (size_t)16 * 128, aDst1);
    gl_lds16(bSrc + ci0, bDst0);
    gl_lds16(bSrc + ci0 + (size_t)16 * 128, bDst1);
    __syncthreads();
    bf16x8 af[4], bv[4];
#pragma unroll
    for (int t = 0; t < 4; t++)
      af[t] = *(const bf16x8*)&As[(wm + t * 16 + l15) * 32 + kq];
#pragma unroll
    for (int t = 0; t < 4; t++)
      bv[t] = *(const bf16x8*)&Bs[(wn + t * 16 + l15) * 32 + kq];
#pragma unroll
    for (int i = 0; i < 4; i++)
#pragma unroll
      for (int j = 0; j < 4; j++)
        acc[i][j] = __builtin_amdgcn_mfma_f32_16x16x32_bf16(af[i], bv[j],
                                                            acc[i][j], 0, 0, 0);
  }

  float* ob = out + (size_t)sp * B * DIMC * HW + (size_t)b * DIMC * HW;
#pragma unroll
  for (int i = 0; i < 4; i++) {
    int corow = wm + i * 16 + q * 4;
#pragma unroll
    for (int j = 0; j < 4; j++) {
      int px = px0 + wn + j * 16 + l15;
#pragma unroll
      for (int r = 0; r < 4; r++)
        ob[(size_t)(corow + r) * HW + px] =
            acc[i][j][r] + bpack[640 + sp * 128 + corow + r];
    }
  }
}

// ---------------------------------------------------------------- launch
extern "C" void kernel_launch(void* const* d_in, const int* in_sizes, int n_in,
                              void* d_out, int out_size, void* d_ws, size_t ws_size,
                              hipStream_t stream) {
  const float* x = (const float*)d_in[0];
  const float* ms = (const float*)d_in[1];
  const float* lpan = (const float*)d_in[2];
  const float* pan = (const float*)d_in[3];
  const float* s = (const float*)d_in[4];
  const float* q_w = (const float*)d_in[5];
  const float* q_b = (const float*)d_in[6];
  const float* k_pan_w = (const float*)d_in[7];
  const float* k_pan_b = (const float*)d_in[8];
  const float* v_pan_w = (const float*)d_in[9];
  const float* v_pan_b = (const float*)d_in[10];
  const float* kv_ms_w = (const float*)d_in[11];
  const float* kv_ms_b = (const float*)d_in[12];
  const float* dep_w = (const float*)d_in[13];
  const float* dep_b = (const float*)d_in[14];
  const float* pp_w = (const float*)d_in[15];
  const float* pp_b = (const float*)d_in[16];
  const float* pm_w = (const float*)d_in[17];
  const float* pm_b = (const float*)d_in[18];
  int B = in_sizes[0] / (DIMC * HW);

  char* ws = (char*)d_ws;
  size_t off = 0;
  auto alloc = [&](size_t bytes) -> void* {
    void* pptr = ws + off;
    off = (off + bytes + 255) & ~(size_t)255;
    return pptr;
  };
  ushort_t* wp2 = (ushort_t*)alloc((size_t)COUT * KTOT * sizeof(ushort_t));
  ushort_t* wproj = (ushort_t*)alloc((size_t)2 * 128 * 128 * sizeof(ushort_t));
  float* bpack = (float*)alloc((size_t)(COUT + 256) * sizeof(float));
  bf16* Y = (bf16*)alloc((size_t)B * COUT * HW * sizeof(bf16));
  // X_T and att_t share the tail region: X_T dead after conv, att_t written after.
  size_t xt_sz = (size_t)B * NPIX * CI_PAD * sizeof(ushort_t);
  size_t att_sz = (size_t)B * 2 * HW * 128 * sizeof(ushort_t);
  ushort_t* xt = (ushort_t*)(ws + off);
  ushort_t* att_t = (ushort_t*)(ws + off);
  off += (att_sz > xt_sz ? att_sz : xt_sz);
  (void)ws_size; (void)n_in; (void)out_size;

  k_prep<<<dim3(2, HSZ + 2, B), 256, 0, stream>>>(x, ms, lpan, pan, s, xt, B);
  k_pack<<<dim3((COUT * CI_PAD + 255) / 256), 256, 0, stream>>>(
      q_w, q_b, k_pan_w, k_pan_b, v_pan_w, v_pan_b, kv_ms_w, kv_ms_b,
      pp_w, pp_b, pm_w, pm_b, wp2, wproj, bpack);
  k_conv_mfma<<<dim3(HSZ, COUT / 128, B), 256, 0, stream>>>(xt, wp2, bpack, Y, B);
  k_attn<<<dim3(HSZ / 4, 2 * NH, B), 256, 0, stream>>>(Y, dep_w, dep_b, att_t, B);
  k_proj_mfma<<<dim3(HW / 128, 1, 2 * B), 256, 0, stream>>>(att_t, wproj, bpack,
                                                            (float*)d_out, B);
}